// Round 3
// baseline (969.497 us; speedup 1.0000x reference)
//
#include <hip/hip_runtime.h>
#include <hip/hip_bf16.h>
#include <math.h>

#define NB 4
#define HH 128
#define WW 128
#define CC 128
#define GG 8
#define GCC 16
#define KK 9
#define NHW (NB*HH*WW)   // 65536

typedef __hip_bfloat16 bf16;

__device__ __forceinline__ float b2f(bf16 v){ return __bfloat162float(v); }
__device__ __forceinline__ bf16 f2b(float v){ return __float2bfloat16(v); }
__device__ __forceinline__ float gelu_f(float v){ return 0.5f*v*(1.f+erff(v*0.70710678118654752f)); }

// ---------------- LayerNorm over C=128, one wave per pixel ----------------
// X: f32 (either the f32 input x or the f32 residual stream in d_out)
__global__ __launch_bounds__(256) void ln_k(const float* __restrict__ X,
    const float* __restrict__ gam, const float* __restrict__ bet, bf16* __restrict__ Y)
{
  int lane = threadIdx.x & 63;
  int wid  = threadIdx.x >> 6;
  size_t pix = (size_t)blockIdx.x*4 + wid;
  const float* xp = X + pix*CC;
  int c0 = lane*2;
  float v0 = xp[c0], v1 = xp[c0+1];
  float s = v0+v1, ss = v0*v0+v1*v1;
  #pragma unroll
  for (int off=32; off>0; off>>=1){ s += __shfl_xor(s,off,64); ss += __shfl_xor(ss,off,64); }
  float mean = s*(1.f/CC);
  float var  = ss*(1.f/CC) - mean*mean;
  float rstd = rsqrtf(var + 1e-5f);
  float y0 = (v0-mean)*rstd*gam[c0]   + bet[c0];
  float y1 = (v1-mean)*rstd*gam[c0+1] + bet[c0+1];
  Y[pix*CC + c0]   = f2b(y0);
  Y[pix*CC + c0+1] = f2b(y1);
}

// ------------- depthwise 3x3 conv (SAME, zero pad) + LN + GELU -------------
__global__ __launch_bounds__(128) void convln_k(const bf16* __restrict__ XN,
    const float* __restrict__ dwk, const float* __restrict__ dwb,
    const float* __restrict__ gam, const float* __restrict__ bet, bf16* __restrict__ X1)
{
  int c = threadIdx.x;
  int pix = blockIdx.x;
  int w = pix & (WW-1); int h = (pix>>7) & (HH-1); int n = pix>>14;
  float acc = dwb[c];
  #pragma unroll
  for (int ky=0; ky<3; ky++){
    int yy = h+ky-1;
    if (yy<0||yy>=HH) continue;
    #pragma unroll
    for (int kx=0; kx<3; kx++){
      int xx = w+kx-1;
      if (xx<0||xx>=WW) continue;
      acc += b2f(XN[(((size_t)(n*HH+yy))*WW+xx)*CC + c]) * dwk[(ky*3+kx)*CC + c];
    }
  }
  // LN over 128 channels (2 waves)
  float s=acc, ss=acc*acc;
  #pragma unroll
  for (int off=32; off>0; off>>=1){ s += __shfl_xor(s,off,64); ss += __shfl_xor(ss,off,64); }
  __shared__ float sred[2], ssred[2];
  int wid = c>>6;
  if ((c&63)==0){ sred[wid]=s; ssred[wid]=ss; }
  __syncthreads();
  float S=sred[0]+sred[1], SS=ssred[0]+ssred[1];
  float mean=S*(1.f/CC), var=SS*(1.f/CC)-mean*mean, rstd=rsqrtf(var+1e-5f);
  float v = (acc-mean)*rstd*gam[c] + bet[c];
  v = gelu_f(v);
  X1[(size_t)pix*CC + c] = f2b(v);
}

// ---- fused: offset/mask projection + softmax + DCNv3 bilinear sampling ----
// padded sample coord reduces to px_pad = w+1 + {-1,0,1}[k/3] + off_x; we
// sample the UNPADDED xp with zero outside [0,128) (equivalent: pad ring is 0)
__global__ __launch_bounds__(128) void dcn_k(const bf16* __restrict__ X1,
    const bf16* __restrict__ XP,
    const float* __restrict__ offw, const float* __restrict__ offb,
    const float* __restrict__ maskw, const float* __restrict__ maskb,
    bf16* __restrict__ Y)
{
  __shared__ float xs[CC];
  __shared__ float offs[GG*KK*2];   // 144
  __shared__ float msk[GG*KK];      // 72
  int t = threadIdx.x;
  int pix = blockIdx.x;
  int w = pix & (WW-1); int h = (pix>>7)&(HH-1); int n = pix>>14;
  xs[t] = b2f(X1[(size_t)pix*CC + t]);
  __syncthreads();
  {   // offset col t (t<128<144 always)
    float acc = offb[t];
    for (int k=0;k<CC;k++) acc += xs[k]*offw[k*(GG*KK*2) + t];
    offs[t] = acc;
  }
  int j = t + 128;
  if (j < GG*KK*2){
    float acc = offb[j];
    for (int k=0;k<CC;k++) acc += xs[k]*offw[k*(GG*KK*2)+j];
    offs[j]=acc;
  } else if (j < GG*KK*2 + GG*KK) {
    int jm = j - GG*KK*2;
    float acc = maskb[jm];
    for (int k=0;k<CC;k++) acc += xs[k]*maskw[k*(GG*KK)+jm];
    msk[jm]=acc;
  }
  __syncthreads();
  if (t < GG){
    float mx=-1e30f;
    for (int k=0;k<KK;k++) mx = fmaxf(mx, msk[t*KK+k]);
    float e[KK]; float sum=0.f;
    for (int k=0;k<KK;k++){ e[k]=expf(msk[t*KK+k]-mx); sum+=e[k]; }
    float inv = 1.f/sum;
    for (int k=0;k<KK;k++) msk[t*KK+k]=e[k]*inv;
  }
  __syncthreads();
  int g = t >> 4;           // group; channel == t (groups are contiguous 16ch)
  float acc = 0.f;
  const bf16* xpn = XP + (size_t)n*HH*WW*CC;
  #pragma unroll
  for (int k=0;k<KK;k++){
    float offx = offs[g*(2*KK) + 2*k];
    float offy = offs[g*(2*KK) + 2*k + 1];
    float px = (float)w + (float)(k/3 - 1) + offx;   // grid is x-major: x idx = k/3
    float py = (float)h + (float)(k%3 - 1) + offy;
    float x0f = floorf(px), y0f = floorf(py);
    float tx = px - x0f, ty = py - y0f;
    int x0 = (int)x0f, y0 = (int)y0f;
    int x1i = x0+1, y1i = y0+1;
    float m = msk[g*KK + k];
    float w00 = (1.f-ty)*(1.f-tx)*m, w01 = (1.f-ty)*tx*m;
    float w10 = ty*(1.f-tx)*m,       w11 = ty*tx*m;
    bool vx0 = (x0>=0)&&(x0<WW),  vx1=(x1i>=0)&&(x1i<WW);
    bool vy0 = (y0>=0)&&(y0<HH),  vy1=(y1i>=0)&&(y1i<HH);
    if (vy0){
      const bf16* row = xpn + ((size_t)y0*WW)*CC;
      if (vx0) acc += w00 * b2f(row[(size_t)x0 *CC + t]);
      if (vx1) acc += w01 * b2f(row[(size_t)x1i*CC + t]);
    }
    if (vy1){
      const bf16* row = xpn + ((size_t)y1i*WW)*CC;
      if (vx0) acc += w10 * b2f(row[(size_t)x0 *CC + t]);
      if (vx1) acc += w11 * b2f(row[(size_t)x1i*CC + t]);
    }
  }
  Y[(size_t)pix*CC + t] = f2b(acc);
}

// --------------- simple fp32 SIMT tiled GEMM: C = A@B (+bias)(+res) ---------------
// A: MxK row-major bf16 (ws staging), B: KxN row-major f32 (weights).
// BM=BN=64, BK=16, 256 thr, 4x4 microtile. OutT: bf16 (ws) or float (d_out).
template<typename OutT, bool RES>
__global__ __launch_bounds__(256) void gemm_k(const bf16* __restrict__ A,
    const float* __restrict__ B, const float* __restrict__ bias,
    const float* __restrict__ res, OutT* __restrict__ Cout,
    int M, int N, int K)
{
  __shared__ float As[16][64];
  __shared__ float Bs[16][68];
  int tid = threadIdx.x;
  int m0 = blockIdx.y*64, n0 = blockIdx.x*64;
  int ty = tid>>4, tx = tid&15;
  float acc[4][4] = {};
  int e = tid*4;
  int ar = e>>4, ac0 = e&15;
  int br = e>>6, bc0 = e&63;
  for (int k0=0; k0<K; k0+=16){
    const bf16* ap = A + (size_t)(m0+ar)*K + k0 + ac0;
    float a0=b2f(ap[0]), a1=b2f(ap[1]), a2=b2f(ap[2]), a3=b2f(ap[3]);
    const float* bp = B + (size_t)(k0+br)*N + n0 + bc0;
    float b0v=bp[0], b1v=bp[1], b2v=bp[2], b3v=bp[3];
    __syncthreads();
    As[ac0+0][ar]=a0; As[ac0+1][ar]=a1; As[ac0+2][ar]=a2; As[ac0+3][ar]=a3;
    Bs[br][bc0+0]=b0v; Bs[br][bc0+1]=b1v; Bs[br][bc0+2]=b2v; Bs[br][bc0+3]=b3v;
    __syncthreads();
    #pragma unroll
    for (int kk=0;kk<16;kk++){
      float av[4], bv[4];
      #pragma unroll
      for (int i=0;i<4;i++) av[i]=As[kk][ty*4+i];
      #pragma unroll
      for (int j=0;j<4;j++) bv[j]=Bs[kk][tx*4+j];
      #pragma unroll
      for (int i=0;i<4;i++)
        #pragma unroll
        for (int jj=0;jj<4;jj++) acc[i][jj] += av[i]*bv[jj];
    }
  }
  #pragma unroll
  for (int i=0;i<4;i++){
    int m = m0 + ty*4 + i;
    #pragma unroll
    for (int jj=0;jj<4;jj++){
      int nn = n0 + tx*4 + jj;
      float v = acc[i][jj] + bias[nn];
      if (RES)  v += res[(size_t)m*N + nn];
      Cout[(size_t)m*N + nn] = (OutT)v;
    }
  }
}

// ------- fused MLP: out = gelu(h0@fc1+b1)@fc2 + b2 + res, K-chunked --------
// block: 256 thr, 64 pixels. LDS: h0 tile (bf16), fc1 chunk, fc2 chunk,
// gelu'd intermediate T (bf16, padded). out acc 64x128 in registers.
// RES/OUT are f32 (d_out, element-wise aliasing within the same thread).
__global__ __launch_bounds__(256) void mlp_k(const bf16* __restrict__ H0,
    const float* __restrict__ w1, const float* __restrict__ b1,
    const float* __restrict__ w2, const float* __restrict__ b2,
    const float* __restrict__ RES, float* __restrict__ OUT)
{
  __shared__ bf16 h0s[64*128];      // 16KB, h0s[m*128+k]
  __shared__ bf16 w1s[128*64];      // 16KB, w1s[k*64+n]
  __shared__ bf16 w2s[64*128];      // 16KB, w2s[k*128+n]
  __shared__ bf16 ts[64*72];        // 9.2KB, ts[m*72+k], padded
  int tid = threadIdx.x;
  int m0 = blockIdx.x * 64;
  #pragma unroll
  for (int i=0;i<32;i++){
    int idx = tid + i*256;
    h0s[idx] = H0[(size_t)m0*128 + idx];
  }
  int ty = tid>>4, tx = tid&15;
  float acc[4][8];
  #pragma unroll
  for(int i=0;i<4;i++)
    #pragma unroll
    for(int j=0;j<8;j++) acc[i][j]=0.f;

  for (int c0=0; c0<512; c0+=64){
    __syncthreads();   // prior chunk's GEMM2 (ts/w2s readers) done; also h0s ready
    #pragma unroll
    for (int i=0;i<32;i++){
      int idx = tid + i*256;          // idx = k*64+n
      int k = idx>>6, n = idx&63;
      w1s[idx] = f2b(w1[(size_t)k*512 + c0 + n]);
    }
    #pragma unroll
    for (int i=0;i<32;i++){
      int idx = tid + i*256;          // idx = k*128+n ; (c0+k)*128+n = c0*128+idx
      w2s[idx] = f2b(w2[(size_t)c0*128 + idx]);
    }
    __syncthreads();
    // GEMM1: T = h0s @ w1s  (64x64, K=128); thread tile 4x4 (m=ty*4+i, n=tx*4+j)
    float t4[4][4];
    #pragma unroll
    for(int i=0;i<4;i++)
      #pragma unroll
      for(int j=0;j<4;j++) t4[i][j]=0.f;
    for (int k=0;k<128;k++){
      float a[4], b[4];
      #pragma unroll
      for(int i=0;i<4;i++) a[i] = b2f(h0s[(ty*4+i)*128 + k]);
      #pragma unroll
      for(int j=0;j<4;j++) b[j] = b2f(w1s[k*64 + tx*4+j]);
      #pragma unroll
      for(int i=0;i<4;i++)
        #pragma unroll
        for(int j=0;j<4;j++) t4[i][j] += a[i]*b[j];
    }
    #pragma unroll
    for(int i=0;i<4;i++)
      #pragma unroll
      for(int j=0;j<4;j++){
        float v = t4[i][j] + b1[c0 + tx*4+j];
        ts[(ty*4+i)*72 + tx*4+j] = f2b(gelu_f(v));
      }
    __syncthreads();
    // GEMM2: acc += T @ w2s  (64x128, K=64); thread tile 4x8 (m=ty*4+i, n=tx*8+j)
    for (int k=0;k<64;k++){
      float a[4], b[8];
      #pragma unroll
      for(int i=0;i<4;i++) a[i] = b2f(ts[(ty*4+i)*72 + k]);
      #pragma unroll
      for(int j=0;j<8;j++) b[j] = b2f(w2s[k*128 + tx*8+j]);
      #pragma unroll
      for(int i=0;i<4;i++)
        #pragma unroll
        for(int j=0;j<8;j++) acc[i][j] += a[i]*b[j];
    }
  }
  #pragma unroll
  for(int i=0;i<4;i++){
    int m = m0 + ty*4 + i;
    #pragma unroll
    for(int j=0;j<8;j++){
      int n = tx*8 + j;
      float v = acc[i][j] + b2[n] + RES[(size_t)m*128 + n];
      OUT[(size_t)m*128 + n] = v;
    }
  }
}

extern "C" void kernel_launch(void* const* d_in, const int* in_sizes, int n_in,
                              void* d_out, int out_size, void* d_ws, size_t ws_size,
                              hipStream_t stream)
{
  const float* x    = (const float*)d_in[0];
  const float* ln1g = (const float*)d_in[1];
  const float* ln1b = (const float*)d_in[2];
  const float* inw  = (const float*)d_in[3];
  const float* inb  = (const float*)d_in[4];
  const float* dwk  = (const float*)d_in[5];
  const float* dwb  = (const float*)d_in[6];
  const float* dwlng= (const float*)d_in[7];
  const float* dwlnb= (const float*)d_in[8];
  const float* offw = (const float*)d_in[9];
  const float* offb = (const float*)d_in[10];
  const float* maskw= (const float*)d_in[11];
  const float* maskb= (const float*)d_in[12];
  const float* outw = (const float*)d_in[13];
  const float* outb = (const float*)d_in[14];
  const float* ln2g = (const float*)d_in[15];
  const float* ln2b = (const float*)d_in[16];
  const float* fc1w = (const float*)d_in[17];
  const float* fc1b = (const float*)d_in[18];
  const float* fc2w = (const float*)d_in[19];
  const float* fc2b = (const float*)d_in[20];
  float* out = (float*)d_out;

  bf16* ws = (bf16*)d_ws;
  const size_t S = (size_t)NHW*CC;  // 8388608 elements
  // ws regions (bf16 elems), total 3S = 48 MB:
  //   R0 [0,S):   xn  -> y
  //   R1 [S,2S):  xp  -> h0
  //   R2 [2S,3S): x1
  // residual stream x2 lives in d_out as f32 (launch 5 writes it; mlp_k reads
  // res + writes out element-wise within the same thread -> safe aliasing).
  bf16* xn = ws;
  bf16* xp = ws + S;
  bf16* x1 = ws + 2*S;
  bf16* y  = xn;
  float* x2 = out;
  bf16* h0 = xp;

  // 1. xn = LN1(x)
  ln_k<<<NHW/4, 256, 0, stream>>>(x, ln1g, ln1b, xn);
  // 2. xp = xn @ in_w + in_b
  gemm_k<bf16,false><<<dim3(2,1024), 256, 0, stream>>>(xn, inw, inb, nullptr, xp, NHW, 128, 128);
  // 3. x1 = gelu(LN(dwconv(xn)))
  convln_k<<<NHW, 128, 0, stream>>>(xn, dwk, dwb, dwlng, dwlnb, x1);
  // 4. y = dcn_core(xp, offset(x1), mask(x1))
  dcn_k<<<NHW, 128, 0, stream>>>(x1, xp, offw, offb, maskw, maskb, y);
  // 5. x2 = x + (y @ out_w + out_b)   [f32, into d_out]
  gemm_k<float,true><<<dim3(2,1024), 256, 0, stream>>>(y, outw, outb, x, x2, NHW, 128, 128);
  // 6. h0 = LN2(x2)
  ln_k<<<NHW/4, 256, 0, stream>>>(x2, ln2g, ln2b, h0);
  // 7. out = x2 + gelu(h0 @ fc1 + b1) @ fc2 + b2   [fused MLP, in-place on d_out]
  mlp_k<<<1024, 256, 0, stream>>>(h0, fc1w, fc1b, fc2w, fc2b, x2, out);
}

// Round 4
// 916.019 us; speedup vs baseline: 1.0584x; 1.0584x over previous
//
#include <hip/hip_runtime.h>
#include <hip/hip_bf16.h>
#include <math.h>

#define NB 4
#define HH 128
#define WW 128
#define CC 128
#define GG 8
#define GCC 16
#define KK 9
#define NHW (NB*HH*WW)   // 65536

typedef __hip_bfloat16 bf16;

__device__ __forceinline__ float b2f(bf16 v){ return __bfloat162float(v); }
__device__ __forceinline__ bf16 f2b(float v){ return __float2bfloat16(v); }
__device__ __forceinline__ float gelu_f(float v){ return 0.5f*v*(1.f+erff(v*0.70710678118654752f)); }
__device__ __forceinline__ float lo_bf(unsigned u){ union{unsigned i; float f;} c; c.i = u<<16; return c.f; }
__device__ __forceinline__ float hi_bf(unsigned u){ union{unsigned i; float f;} c; c.i = u&0xffff0000u; return c.f; }

// ---------------- LayerNorm over C=128, one wave per pixel ----------------
__global__ __launch_bounds__(256) void ln_k(const float* __restrict__ X,
    const float* __restrict__ gam, const float* __restrict__ bet, bf16* __restrict__ Y)
{
  int lane = threadIdx.x & 63;
  int wid  = threadIdx.x >> 6;
  size_t pix = (size_t)blockIdx.x*4 + wid;
  const float* xp = X + pix*CC;
  int c0 = lane*2;
  float v0 = xp[c0], v1 = xp[c0+1];
  float s = v0+v1, ss = v0*v0+v1*v1;
  #pragma unroll
  for (int off=32; off>0; off>>=1){ s += __shfl_xor(s,off,64); ss += __shfl_xor(ss,off,64); }
  float mean = s*(1.f/CC);
  float var  = ss*(1.f/CC) - mean*mean;
  float rstd = rsqrtf(var + 1e-5f);
  float y0 = (v0-mean)*rstd*gam[c0]   + bet[c0];
  float y1 = (v1-mean)*rstd*gam[c0+1] + bet[c0+1];
  Y[pix*CC + c0]   = f2b(y0);
  Y[pix*CC + c0+1] = f2b(y1);
}

// ------------- depthwise 3x3 conv (SAME, zero pad) + LN + GELU -------------
__global__ __launch_bounds__(128) void convln_k(const bf16* __restrict__ XN,
    const float* __restrict__ dwk, const float* __restrict__ dwb,
    const float* __restrict__ gam, const float* __restrict__ bet, bf16* __restrict__ X1)
{
  int c = threadIdx.x;
  int pix = blockIdx.x;
  int w = pix & (WW-1); int h = (pix>>7) & (HH-1); int n = pix>>14;
  float acc = dwb[c];
  #pragma unroll
  for (int ky=0; ky<3; ky++){
    int yy = h+ky-1;
    if (yy<0||yy>=HH) continue;
    #pragma unroll
    for (int kx=0; kx<3; kx++){
      int xx = w+kx-1;
      if (xx<0||xx>=WW) continue;
      acc += b2f(XN[(((size_t)(n*HH+yy))*WW+xx)*CC + c]) * dwk[(ky*3+kx)*CC + c];
    }
  }
  float s=acc, ss=acc*acc;
  #pragma unroll
  for (int off=32; off>0; off>>=1){ s += __shfl_xor(s,off,64); ss += __shfl_xor(ss,off,64); }
  __shared__ float sred[2], ssred[2];
  int wid = c>>6;
  if ((c&63)==0){ sred[wid]=s; ssred[wid]=ss; }
  __syncthreads();
  float S=sred[0]+sred[1], SS=ssred[0]+ssred[1];
  float mean=S*(1.f/CC), var=SS*(1.f/CC)-mean*mean, rstd=rsqrtf(var+1e-5f);
  float v = (acc-mean)*rstd*gam[c] + bet[c];
  v = gelu_f(v);
  X1[(size_t)pix*CC + c] = f2b(v);
}

// ---- fused DCN: tiled projection GEMM + softmax + bilinear sampling ----
// Block = 64 consecutive pixels of one image row (W=128 -> 2 segs/row).
// Phase 1: OM(64x224) = x1_tile(64x128) @ [offw|maskw|pad] + bias, LDS-tiled.
// Phase 2: softmax over each (pixel, group)'s 9 mask scores, in LDS.
// Phase 3: bilinear sampling; thread = (ch-pair, pixel-slot), 16 pixel iters.
// padded sample coord reduces to px = w + (k/3-1) + offx (x-major grid),
// sampling UNPADDED xp with zero outside [0,128).
__global__ __launch_bounds__(256) void samp_k(const bf16* __restrict__ X1,
    const bf16* __restrict__ XP,
    const float* __restrict__ offw, const float* __restrict__ offb,
    const float* __restrict__ maskw, const float* __restrict__ maskb,
    bf16* __restrict__ Y)
{
  __shared__ bf16  x1s[64*136];    // 17.4KB, row stride 136 (2-way-free banks, 16B-aligned rows)
  __shared__ float wcs[16*224];    // 14.3KB, k-chunk of combined weights
  __shared__ bf16  oms[64*224];    // 28.7KB, scores -> softmax'd masks
  int tid = threadIdx.x;
  int pix0 = blockIdx.x*64;

  { // load x1 tile: thread m=tid>>2, 32-ch quarter cq
    int m = tid>>2, cq = (tid&3)*32;
    const uint4* src = (const uint4*)(X1 + (size_t)(pix0+m)*CC + cq);
    uint4* dst = (uint4*)(&x1s[m*136 + cq]);
    #pragma unroll
    for (int i=0;i<4;i++) dst[i] = src[i];
  }

  int ty = tid>>4, tx = tid&15;   // GEMM: m = ty*4+i (4), n = tx*14+j (14)
  float acc[4][14];
  #pragma unroll
  for (int i=0;i<4;i++)
    #pragma unroll
    for (int j=0;j<14;j++) acc[i][j]=0.f;

  for (int k0=0;k0<128;k0+=16){
    __syncthreads();   // x1s ready (first iter); wcs consumers done (later iters)
    { // stage weight chunk rows k0..k0+15, combined cols [offw(144)|maskw(72)|0(8)]
      int r = tid>>4, jb = (tid&15)*14;
      #pragma unroll
      for (int jj=0;jj<14;jj++){
        int j = jb+jj; int k = k0+r;
        float v;
        if (j < 144)      v = offw[(size_t)k*144 + j];
        else if (j < 216) v = maskw[(size_t)k*72 + (j-144)];
        else              v = 0.f;
        wcs[r*224 + j] = v;
      }
    }
    __syncthreads();
    for (int k=0;k<16;k++){
      float a[4], b[14];
      #pragma unroll
      for (int i=0;i<4;i++) a[i] = b2f(x1s[(ty*4+i)*136 + k0+k]);
      #pragma unroll
      for (int j=0;j<14;j++) b[j] = wcs[k*224 + tx*14 + j];
      #pragma unroll
      for (int i=0;i<4;i++)
        #pragma unroll
        for (int j=0;j<14;j++) acc[i][j] += a[i]*b[j];
    }
  }
  // epilogue: bias, write scores to oms (bf16)
  {
    float bias[14];
    #pragma unroll
    for (int j=0;j<14;j++){
      int col = tx*14+j;
      bias[j] = (col<144) ? offb[col] : (col<216 ? maskb[col-144] : 0.f);
    }
    __syncthreads();  // all wcs/x1s reads done before oms overwrites nothing, but order barrier anyway
    #pragma unroll
    for (int i=0;i<4;i++)
      #pragma unroll
      for (int j=0;j<14;j++)
        oms[(ty*4+i)*224 + tx*14+j] = f2b(acc[i][j] + bias[j]);
  }
  __syncthreads();
  // softmax: 64 px * 8 groups = 512 tasks
  for (int task=tid; task<512; task+=256){
    int m = task>>3, g = task&7;
    int base = m*224 + 144 + g*9;
    float sc[9]; float mx = -1e30f;
    #pragma unroll
    for (int k=0;k<9;k++){ sc[k] = b2f(oms[base+k]); mx = fmaxf(mx, sc[k]); }
    float sum = 0.f;
    #pragma unroll
    for (int k=0;k<9;k++){ sc[k] = expf(sc[k]-mx); sum += sc[k]; }
    float inv = 1.f/sum;
    #pragma unroll
    for (int k=0;k<9;k++) oms[base+k] = f2b(sc[k]*inv);
  }
  __syncthreads();
  // sampling: thread = pair (0..63) x slot (0..3); 16 pixel iterations
  int pair = tid>>2, s = tid&3;
  int g = pair>>3;
  int ch = g*GCC + (pair&7)*2;
  int w0 = pix0 & (WW-1);
  int h  = (pix0>>7) & (HH-1);
  int n  = pix0>>14;
  const bf16* xpn = XP + (size_t)n*HH*WW*CC;
  for (int it=0; it<16; it++){
    int m = it*4 + s;
    int wc = w0 + m;
    const bf16* omrow = &oms[m*224];
    float ax=0.f, ay=0.f;
    #pragma unroll
    for (int k=0;k<9;k++){
      float offx = b2f(omrow[g*18 + 2*k]);
      float offy = b2f(omrow[g*18 + 2*k + 1]);
      float mk   = b2f(omrow[144 + g*9 + k]);
      float pxf = (float)(wc + (k/3) - 1) + offx;
      float pyf = (float)(h  + (k%3) - 1) + offy;
      float x0f = floorf(pxf), y0f = floorf(pyf);
      float txf = pxf-x0f,     tyf = pyf-y0f;
      int x0 = (int)x0f, y0 = (int)y0f;
      int x1i = x0+1,    y1i = y0+1;
      float w00=(1.f-tyf)*(1.f-txf)*mk, w01=(1.f-tyf)*txf*mk;
      float w10=tyf*(1.f-txf)*mk,       w11=tyf*txf*mk;
      bool vx0=((unsigned)x0<(unsigned)WW), vx1=((unsigned)x1i<(unsigned)WW);
      bool vy0=((unsigned)y0<(unsigned)HH), vy1=((unsigned)y1i<(unsigned)HH);
      if (vy0){
        const unsigned* row = (const unsigned*)(xpn + ((size_t)y0*WW)*CC + ch);
        if (vx0){ unsigned u = row[x0*64];  ax += w00*lo_bf(u); ay += w00*hi_bf(u); }
        if (vx1){ unsigned u = row[x1i*64]; ax += w01*lo_bf(u); ay += w01*hi_bf(u); }
      }
      if (vy1){
        const unsigned* row = (const unsigned*)(xpn + ((size_t)y1i*WW)*CC + ch);
        if (vx0){ unsigned u = row[x0*64];  ax += w10*lo_bf(u); ay += w10*hi_bf(u); }
        if (vx1){ unsigned u = row[x1i*64]; ax += w11*lo_bf(u); ay += w11*hi_bf(u); }
      }
    }
    unsigned outp = ((unsigned)__bfloat16_as_ushort(f2b(ay))<<16) | (unsigned)__bfloat16_as_ushort(f2b(ax));
    *(unsigned*)(Y + (size_t)(pix0+m)*CC + ch) = outp;
  }
}

// --------------- simple fp32 SIMT tiled GEMM: C = A@B (+bias)(+res) ---------------
template<typename OutT, bool RES>
__global__ __launch_bounds__(256) void gemm_k(const bf16* __restrict__ A,
    const float* __restrict__ B, const float* __restrict__ bias,
    const float* __restrict__ res, OutT* __restrict__ Cout,
    int M, int N, int K)
{
  __shared__ float As[16][64];
  __shared__ float Bs[16][68];
  int tid = threadIdx.x;
  int m0 = blockIdx.y*64, n0 = blockIdx.x*64;
  int ty = tid>>4, tx = tid&15;
  float acc[4][4] = {};
  int e = tid*4;
  int ar = e>>4, ac0 = e&15;
  int br = e>>6, bc0 = e&63;
  for (int k0=0; k0<K; k0+=16){
    const bf16* ap = A + (size_t)(m0+ar)*K + k0 + ac0;
    float a0=b2f(ap[0]), a1=b2f(ap[1]), a2=b2f(ap[2]), a3=b2f(ap[3]);
    const float* bp = B + (size_t)(k0+br)*N + n0 + bc0;
    float b0v=bp[0], b1v=bp[1], b2v=bp[2], b3v=bp[3];
    __syncthreads();
    As[ac0+0][ar]=a0; As[ac0+1][ar]=a1; As[ac0+2][ar]=a2; As[ac0+3][ar]=a3;
    Bs[br][bc0+0]=b0v; Bs[br][bc0+1]=b1v; Bs[br][bc0+2]=b2v; Bs[br][bc0+3]=b3v;
    __syncthreads();
    #pragma unroll
    for (int kk=0;kk<16;kk++){
      float av[4], bv[4];
      #pragma unroll
      for (int i=0;i<4;i++) av[i]=As[kk][ty*4+i];
      #pragma unroll
      for (int j=0;j<4;j++) bv[j]=Bs[kk][tx*4+j];
      #pragma unroll
      for (int i=0;i<4;i++)
        #pragma unroll
        for (int jj=0;jj<4;jj++) acc[i][jj] += av[i]*bv[jj];
    }
  }
  #pragma unroll
  for (int i=0;i<4;i++){
    int m = m0 + ty*4 + i;
    #pragma unroll
    for (int jj=0;jj<4;jj++){
      int nn = n0 + tx*4 + jj;
      float v = acc[i][jj] + bias[nn];
      if (RES)  v += res[(size_t)m*N + nn];
      Cout[(size_t)m*N + nn] = (OutT)v;
    }
  }
}

// ------- fused MLP: out = gelu(h0@fc1+b1)@fc2 + b2 + res, K-chunked --------
__global__ __launch_bounds__(256) void mlp_k(const bf16* __restrict__ H0,
    const float* __restrict__ w1, const float* __restrict__ b1,
    const float* __restrict__ w2, const float* __restrict__ b2,
    const float* __restrict__ RES, float* __restrict__ OUT)
{
  __shared__ bf16 h0s[64*128];
  __shared__ bf16 w1s[128*64];
  __shared__ bf16 w2s[64*128];
  __shared__ bf16 ts[64*72];
  int tid = threadIdx.x;
  int m0 = blockIdx.x * 64;
  #pragma unroll
  for (int i=0;i<32;i++){
    int idx = tid + i*256;
    h0s[idx] = H0[(size_t)m0*128 + idx];
  }
  int ty = tid>>4, tx = tid&15;
  float acc[4][8];
  #pragma unroll
  for(int i=0;i<4;i++)
    #pragma unroll
    for(int j=0;j<8;j++) acc[i][j]=0.f;

  for (int c0=0; c0<512; c0+=64){
    __syncthreads();
    #pragma unroll
    for (int i=0;i<32;i++){
      int idx = tid + i*256;
      int k = idx>>6, n = idx&63;
      w1s[idx] = f2b(w1[(size_t)k*512 + c0 + n]);
    }
    #pragma unroll
    for (int i=0;i<32;i++){
      int idx = tid + i*256;
      w2s[idx] = f2b(w2[(size_t)c0*128 + idx]);
    }
    __syncthreads();
    float t4[4][4];
    #pragma unroll
    for(int i=0;i<4;i++)
      #pragma unroll
      for(int j=0;j<4;j++) t4[i][j]=0.f;
    for (int k=0;k<128;k++){
      float a[4], b[4];
      #pragma unroll
      for(int i=0;i<4;i++) a[i] = b2f(h0s[(ty*4+i)*128 + k]);
      #pragma unroll
      for(int j=0;j<4;j++) b[j] = b2f(w1s[k*64 + tx*4+j]);
      #pragma unroll
      for(int i=0;i<4;i++)
        #pragma unroll
        for(int j=0;j<4;j++) t4[i][j] += a[i]*b[j];
    }
    #pragma unroll
    for(int i=0;i<4;i++)
      #pragma unroll
      for(int j=0;j<4;j++){
        float v = t4[i][j] + b1[c0 + tx*4+j];
        ts[(ty*4+i)*72 + tx*4+j] = f2b(gelu_f(v));
      }
    __syncthreads();
    for (int k=0;k<64;k++){
      float a[4], b[8];
      #pragma unroll
      for(int i=0;i<4;i++) a[i] = b2f(ts[(ty*4+i)*72 + k]);
      #pragma unroll
      for(int j=0;j<8;j++) b[j] = b2f(w2s[k*128 + tx*8+j]);
      #pragma unroll
      for(int i=0;i<4;i++)
        #pragma unroll
        for(int j=0;j<8;j++) acc[i][j] += a[i]*b[j];
    }
  }
  #pragma unroll
  for(int i=0;i<4;i++){
    int m = m0 + ty*4 + i;
    #pragma unroll
    for(int j=0;j<8;j++){
      int n = tx*8 + j;
      float v = acc[i][j] + b2[n] + RES[(size_t)m*128 + n];
      OUT[(size_t)m*128 + n] = v;
    }
  }
}

extern "C" void kernel_launch(void* const* d_in, const int* in_sizes, int n_in,
                              void* d_out, int out_size, void* d_ws, size_t ws_size,
                              hipStream_t stream)
{
  const float* x    = (const float*)d_in[0];
  const float* ln1g = (const float*)d_in[1];
  const float* ln1b = (const float*)d_in[2];
  const float* inw  = (const float*)d_in[3];
  const float* inb  = (const float*)d_in[4];
  const float* dwk  = (const float*)d_in[5];
  const float* dwb  = (const float*)d_in[6];
  const float* dwlng= (const float*)d_in[7];
  const float* dwlnb= (const float*)d_in[8];
  const float* offw = (const float*)d_in[9];
  const float* offb = (const float*)d_in[10];
  const float* maskw= (const float*)d_in[11];
  const float* maskb= (const float*)d_in[12];
  const float* outw = (const float*)d_in[13];
  const float* outb = (const float*)d_in[14];
  const float* ln2g = (const float*)d_in[15];
  const float* ln2b = (const float*)d_in[16];
  const float* fc1w = (const float*)d_in[17];
  const float* fc1b = (const float*)d_in[18];
  const float* fc2w = (const float*)d_in[19];
  const float* fc2b = (const float*)d_in[20];
  float* out = (float*)d_out;

  bf16* ws = (bf16*)d_ws;
  const size_t S = (size_t)NHW*CC;
  // ws regions (bf16 elems), total 3S = 48 MB (proven):
  //   R0 [0,S):   xn  -> y      R1 [S,2S): xp -> h0      R2 [2S,3S): x1
  bf16* xn = ws;
  bf16* xp = ws + S;
  bf16* x1 = ws + 2*S;
  bf16* y  = xn;
  float* x2 = out;
  bf16* h0 = xp;

  // 1. xn = LN1(x)
  ln_k<<<NHW/4, 256, 0, stream>>>(x, ln1g, ln1b, xn);
  // 2. xp = xn @ in_w + in_b
  gemm_k<bf16,false><<<dim3(2,1024), 256, 0, stream>>>(xn, inw, inb, nullptr, xp, NHW, 128, 128);
  // 3. x1 = gelu(LN(dwconv(xn)))
  convln_k<<<NHW, 128, 0, stream>>>(xn, dwk, dwb, dwlng, dwlnb, x1);
  // 4. y = dcn_core(xp, offset(x1), mask(x1))  [fused tile kernel]
  samp_k<<<NHW/64, 256, 0, stream>>>(x1, xp, offw, offb, maskw, maskb, y);
  // 5. x2 = x + (y @ out_w + out_b)   [f32, into d_out]
  gemm_k<float,true><<<dim3(2,1024), 256, 0, stream>>>(y, outw, outb, x, x2, NHW, 128, 128);
  // 6. h0 = LN2(x2)
  ln_k<<<NHW/4, 256, 0, stream>>>(x2, ln2g, ln2b, h0);
  // 7. out = x2 + gelu(h0 @ fc1 + b1) @ fc2 + b2
  mlp_k<<<1024, 256, 0, stream>>>(h0, fc1w, fc1b, fc2w, fc2b, x2, out);
}

// Round 5
// 585.197 us; speedup vs baseline: 1.6567x; 1.5653x over previous
//
#include <hip/hip_runtime.h>
#include <hip/hip_bf16.h>
#include <math.h>

#define NB 4
#define HH 128
#define WW 128
#define CC 128
#define GG 8
#define GCC 16
#define KK 9
#define NHW (NB*HH*WW)   // 65536

typedef __hip_bfloat16 bf16;
typedef __attribute__((ext_vector_type(8))) short short8;
typedef __attribute__((ext_vector_type(4))) float f32x4;

__device__ __forceinline__ float b2f(bf16 v){ return __bfloat162float(v); }
__device__ __forceinline__ bf16 f2b(float v){ return __float2bfloat16(v); }
__device__ __forceinline__ float gelu_f(float v){ return 0.5f*v*(1.f+erff(v*0.70710678118654752f)); }
__device__ __forceinline__ float lo_bf(unsigned u){ union{unsigned i; float f;} c; c.i = u<<16; return c.f; }
__device__ __forceinline__ float hi_bf(unsigned u){ union{unsigned i; float f;} c; c.i = u&0xffff0000u; return c.f; }
__device__ __forceinline__ void st_out(bf16* p, float v){ *p = f2b(v); }
__device__ __forceinline__ void st_out(float* p, float v){ *p = v; }

// -------- weight transpose + bf16 cvt: Wt[n*K+k] = W[k*N+n] --------
__global__ __launch_bounds__(256) void tr_k(const float* __restrict__ W,
    bf16* __restrict__ Wt, int kshift, int N, int total)
{
  int idx = blockIdx.x*256 + threadIdx.x;
  if (idx >= total) return;
  int n = idx >> kshift;
  int k = idx & ((1<<kshift)-1);
  Wt[idx] = f2b(W[(size_t)k*N + n]);
}

// ---------------- LayerNorm over C=128, one wave per pixel ----------------
__global__ __launch_bounds__(256) void ln_k(const float* __restrict__ X,
    const float* __restrict__ gam, const float* __restrict__ bet, bf16* __restrict__ Y)
{
  int lane = threadIdx.x & 63;
  int wid  = threadIdx.x >> 6;
  size_t pix = (size_t)blockIdx.x*4 + wid;
  const float* xp = X + pix*CC;
  int c0 = lane*2;
  float v0 = xp[c0], v1 = xp[c0+1];
  float s = v0+v1, ss = v0*v0+v1*v1;
  #pragma unroll
  for (int off=32; off>0; off>>=1){ s += __shfl_xor(s,off,64); ss += __shfl_xor(ss,off,64); }
  float mean = s*(1.f/CC);
  float var  = ss*(1.f/CC) - mean*mean;
  float rstd = rsqrtf(var + 1e-5f);
  float y0 = (v0-mean)*rstd*gam[c0]   + bet[c0];
  float y1 = (v1-mean)*rstd*gam[c0+1] + bet[c0+1];
  Y[pix*CC + c0]   = f2b(y0);
  Y[pix*CC + c0+1] = f2b(y1);
}

// ------------- depthwise 3x3 conv (SAME, zero pad) + LN + GELU -------------
__global__ __launch_bounds__(128) void convln_k(const bf16* __restrict__ XN,
    const float* __restrict__ dwk, const float* __restrict__ dwb,
    const float* __restrict__ gam, const float* __restrict__ bet, bf16* __restrict__ X1)
{
  int c = threadIdx.x;
  int pix = blockIdx.x;
  int w = pix & (WW-1); int h = (pix>>7) & (HH-1); int n = pix>>14;
  float acc = dwb[c];
  #pragma unroll
  for (int ky=0; ky<3; ky++){
    int yy = h+ky-1;
    if (yy<0||yy>=HH) continue;
    #pragma unroll
    for (int kx=0; kx<3; kx++){
      int xx = w+kx-1;
      if (xx<0||xx>=WW) continue;
      acc += b2f(XN[(((size_t)(n*HH+yy))*WW+xx)*CC + c]) * dwk[(ky*3+kx)*CC + c];
    }
  }
  float s=acc, ss=acc*acc;
  #pragma unroll
  for (int off=32; off>0; off>>=1){ s += __shfl_xor(s,off,64); ss += __shfl_xor(ss,off,64); }
  __shared__ float sred[2], ssred[2];
  int wid = c>>6;
  if ((c&63)==0){ sred[wid]=s; ssred[wid]=ss; }
  __syncthreads();
  float S=sred[0]+sred[1], SS=ssred[0]+ssred[1];
  float mean=S*(1.f/CC), var=SS*(1.f/CC)-mean*mean, rstd=rsqrtf(var+1e-5f);
  float v = (acc-mean)*rstd*gam[c] + bet[c];
  v = gelu_f(v);
  X1[(size_t)pix*CC + c] = f2b(v);
}

// ---- fused DCN: tiled projection GEMM + softmax + bilinear sampling ----
// LDS aliased: phase-1 buffers (x1s, wcs) die before oms (scores) is written.
#define OMS 226   // oms row stride (bf16): 113 dwords, odd -> banks spread
__global__ __launch_bounds__(256) void samp_k(const bf16* __restrict__ X1,
    const bf16* __restrict__ XP,
    const float* __restrict__ offw, const float* __restrict__ offb,
    const float* __restrict__ maskw, const float* __restrict__ maskb,
    bf16* __restrict__ Y)
{
  __shared__ __align__(16) char smem[31744];
  bf16*  x1s = (bf16*)smem;             // 64*136 bf16 = 17408 B
  float* wcs = (float*)(smem + 17408);  // 16*224 f32  = 14336 B
  bf16*  oms = (bf16*)smem;             // 64*226 bf16 = 28928 B (aliases x1s/wcs)
  int tid = threadIdx.x;
  int pix0 = blockIdx.x*64;

  { // load x1 tile: thread m=tid>>2, 32-ch quarter cq
    int m = tid>>2, cq = (tid&3)*32;
    const uint4* src = (const uint4*)(X1 + (size_t)(pix0+m)*CC + cq);
    uint4* dst = (uint4*)(&x1s[m*136 + cq]);
    #pragma unroll
    for (int i=0;i<4;i++) dst[i] = src[i];
  }

  int ty = tid>>4, tx = tid&15;   // GEMM: m = ty*4+i (4), n = tx*14+j (14)
  float acc[4][14];
  #pragma unroll
  for (int i=0;i<4;i++)
    #pragma unroll
    for (int j=0;j<14;j++) acc[i][j]=0.f;

  for (int k0=0;k0<128;k0+=16){
    __syncthreads();   // x1s ready (first iter); wcs consumers done (later iters)
    { // stage weight chunk rows k0..k0+15, cols [offw(144)|maskw(72)|0(8)]
      int r = tid>>4, jb = (tid&15)*14;
      #pragma unroll
      for (int jj=0;jj<14;jj++){
        int j = jb+jj; int k = k0+r;
        float v;
        if (j < 144)      v = offw[(size_t)k*144 + j];
        else if (j < 216) v = maskw[(size_t)k*72 + (j-144)];
        else              v = 0.f;
        wcs[r*224 + j] = v;
      }
    }
    __syncthreads();
    for (int k=0;k<16;k++){
      float a[4], b[14];
      #pragma unroll
      for (int i=0;i<4;i++) a[i] = b2f(x1s[(ty*4+i)*136 + k0+k]);
      #pragma unroll
      for (int j=0;j<14;j++) b[j] = wcs[k*224 + tx*14 + j];
      #pragma unroll
      for (int i=0;i<4;i++)
        #pragma unroll
        for (int j=0;j<14;j++) acc[i][j] += a[i]*b[j];
    }
  }
  // epilogue: bias, write scores to oms (aliases x1s/wcs -- dead now)
  {
    float bias[14];
    #pragma unroll
    for (int j=0;j<14;j++){
      int col = tx*14+j;
      bias[j] = (col<144) ? offb[col] : (col<216 ? maskb[col-144] : 0.f);
    }
    __syncthreads();  // all x1s/wcs reads complete before oms overwrites them
    #pragma unroll
    for (int i=0;i<4;i++)
      #pragma unroll
      for (int j=0;j<14;j++)
        oms[(ty*4+i)*OMS + tx*14+j] = f2b(acc[i][j] + bias[j]);
  }
  __syncthreads();
  // softmax: 64 px * 8 groups = 512 tasks
  for (int task=tid; task<512; task+=256){
    int m = task>>3, g = task&7;
    int base = m*OMS + 144 + g*9;
    float sc[9]; float mx = -1e30f;
    #pragma unroll
    for (int k=0;k<9;k++){ sc[k] = b2f(oms[base+k]); mx = fmaxf(mx, sc[k]); }
    float sum = 0.f;
    #pragma unroll
    for (int k=0;k<9;k++){ sc[k] = expf(sc[k]-mx); sum += sc[k]; }
    float inv = 1.f/sum;
    #pragma unroll
    for (int k=0;k<9;k++) oms[base+k] = f2b(sc[k]*inv);
  }
  __syncthreads();
  // sampling: thread = ch-quad (0..31) x slot (0..7); 8 pixel iterations
  int qd = tid>>3, s = tid&7;
  int g = qd>>2;
  int ch = g*GCC + (qd&3)*4;
  int w0 = pix0 & (WW-1);
  int h  = (pix0>>7) & (HH-1);
  int n  = pix0>>14;
  const bf16* xpn = XP + (size_t)n*HH*WW*CC;
  for (int it=0; it<8; it++){
    int m = it*8 + s;
    int wc = w0 + m;
    const bf16* omrow = &oms[m*OMS];
    float a0=0.f, a1=0.f, a2=0.f, a3=0.f;
    #pragma unroll
    for (int k=0;k<9;k++){
      float offx = b2f(omrow[g*18 + 2*k]);
      float offy = b2f(omrow[g*18 + 2*k + 1]);
      float mk   = b2f(omrow[144 + g*9 + k]);
      float pxf = (float)(wc + (k/3) - 1) + offx;
      float pyf = (float)(h  + (k%3) - 1) + offy;
      float x0f = floorf(pxf), y0f = floorf(pyf);
      float txf = pxf-x0f,     tyf = pyf-y0f;
      int x0 = (int)x0f, y0 = (int)y0f;
      int x1i = x0+1,    y1i = y0+1;
      float w00=(1.f-tyf)*(1.f-txf)*mk, w01=(1.f-tyf)*txf*mk;
      float w10=tyf*(1.f-txf)*mk,       w11=tyf*txf*mk;
      bool vx0=((unsigned)x0<(unsigned)WW), vx1=((unsigned)x1i<(unsigned)WW);
      bool vy0=((unsigned)y0<(unsigned)HH), vy1=((unsigned)y1i<(unsigned)HH);
      if (vy0){
        const bf16* rowp = xpn + ((size_t)y0*WW)*CC + ch;
        if (vx0){ uint2 u = *(const uint2*)(rowp + (size_t)x0*CC);
          a0 += w00*lo_bf(u.x); a1 += w00*hi_bf(u.x); a2 += w00*lo_bf(u.y); a3 += w00*hi_bf(u.y); }
        if (vx1){ uint2 u = *(const uint2*)(rowp + (size_t)x1i*CC);
          a0 += w01*lo_bf(u.x); a1 += w01*hi_bf(u.x); a2 += w01*lo_bf(u.y); a3 += w01*hi_bf(u.y); }
      }
      if (vy1){
        const bf16* rowp = xpn + ((size_t)y1i*WW)*CC + ch;
        if (vx0){ uint2 u = *(const uint2*)(rowp + (size_t)x0*CC);
          a0 += w10*lo_bf(u.x); a1 += w10*hi_bf(u.x); a2 += w10*lo_bf(u.y); a3 += w10*hi_bf(u.y); }
        if (vx1){ uint2 u = *(const uint2*)(rowp + (size_t)x1i*CC);
          a0 += w11*lo_bf(u.x); a1 += w11*hi_bf(u.x); a2 += w11*lo_bf(u.y); a3 += w11*hi_bf(u.y); }
      }
    }
    uint2 outp;
    outp.x = ((unsigned)__bfloat16_as_ushort(f2b(a1))<<16) | (unsigned)__bfloat16_as_ushort(f2b(a0));
    outp.y = ((unsigned)__bfloat16_as_ushort(f2b(a3))<<16) | (unsigned)__bfloat16_as_ushort(f2b(a2));
    *(uint2*)(Y + (size_t)(pix0+m)*CC + ch) = outp;
  }
}

// ------------- MFMA GEMM: C(Mx128) = A(Mx128 bf16) @ Bt^T + bias (+res) -------------
// Bt is [N][K] bf16 (pre-transposed). No LDS, no barriers: A-frags stream from
// global (16B/lane), B-frags preloaded to registers (L2-hot).
// Layouts (m89/m91/m120): A[m=l&15][k=quad*8+j], B[k=quad*8+j][n=l&15],
// D[row=quad*4+r][col=l&15].
template<typename OutT, bool RES>
__global__ __launch_bounds__(256) void gemm_mfma(const bf16* __restrict__ A,
    const bf16* __restrict__ Bt, const float* __restrict__ bias,
    const float* __restrict__ res, OutT* __restrict__ C)
{
  int tid = threadIdx.x;
  int wave = tid>>6, l = tid&63, lo16 = l&15, quad = l>>4;
  int m0 = blockIdx.y*128 + wave*32;
  int n0 = blockIdx.x*64;
  short8 bfr[4][4];   // [kstep][ntile]
  #pragma unroll
  for (int ks=0;ks<4;ks++)
    #pragma unroll
    for (int nt=0;nt<4;nt++)
      bfr[ks][nt] = *(const short8*)(Bt + (size_t)(n0+nt*16+lo16)*128 + ks*32 + quad*8);
  f32x4 z = {0.f,0.f,0.f,0.f};
  f32x4 acc[2][4];
  #pragma unroll
  for (int mt=0;mt<2;mt++)
    #pragma unroll
    for (int nt=0;nt<4;nt++) acc[mt][nt]=z;
  #pragma unroll
  for (int ks=0;ks<4;ks++){
    short8 af0 = *(const short8*)(A + (size_t)(m0+lo16)*128    + ks*32 + quad*8);
    short8 af1 = *(const short8*)(A + (size_t)(m0+16+lo16)*128 + ks*32 + quad*8);
    #pragma unroll
    for (int nt=0;nt<4;nt++){
      acc[0][nt] = __builtin_amdgcn_mfma_f32_16x16x32_bf16(af0, bfr[ks][nt], acc[0][nt], 0,0,0);
      acc[1][nt] = __builtin_amdgcn_mfma_f32_16x16x32_bf16(af1, bfr[ks][nt], acc[1][nt], 0,0,0);
    }
  }
  #pragma unroll
  for (int mt=0;mt<2;mt++)
    #pragma unroll
    for (int nt=0;nt<4;nt++){
      int col = n0 + nt*16 + lo16;
      float bb = bias[col];
      #pragma unroll
      for (int r=0;r<4;r++){
        int row = m0 + mt*16 + quad*4 + r;
        float v = acc[mt][nt][r] + bb;
        if (RES) v += res[(size_t)row*128 + col];
        st_out(&C[(size_t)row*128 + col], v);
      }
    }
}

// ---- fused MFMA MLP: out = gelu(h0@fc1+b1)@fc2 + b2 + res, chunked over 512 ----
// w1t: [512][128] bf16, w2t: [128][512] bf16 (pre-transposed).
// Intermediate chunk (64x64) round-trips through LDS: C-layout -> A-layout.
__global__ __launch_bounds__(256) void mlp_mfma(const bf16* __restrict__ H0,
    const bf16* __restrict__ w1t, const float* __restrict__ b1,
    const bf16* __restrict__ w2t, const float* __restrict__ b2,
    const float* __restrict__ RES, float* __restrict__ OUT)
{
  __shared__ bf16 ts[64*72];   // 9.2 KB, row stride 72 (16B-aligned rows)
  int tid = threadIdx.x;
  int wave = tid>>6, l = tid&63, lo16 = l&15, quad = l>>4;
  int m0 = blockIdx.x*64;
  int mw = m0 + wave*16;
  short8 a1[4];
  #pragma unroll
  for (int ks=0;ks<4;ks++)
    a1[ks] = *(const short8*)(H0 + (size_t)(mw+lo16)*128 + ks*32 + quad*8);
  f32x4 z = {0.f,0.f,0.f,0.f};
  f32x4 acc2[8];
  #pragma unroll
  for (int nt=0;nt<8;nt++) acc2[nt]=z;

  for (int c0=0;c0<512;c0+=64){
    // GEMM1: t(64x64) = h0 @ w1[:, c0:c0+64]
    f32x4 acc1[4];
    #pragma unroll
    for (int nt=0;nt<4;nt++) acc1[nt]=z;
    #pragma unroll
    for (int ks=0;ks<4;ks++)
      #pragma unroll
      for (int nt=0;nt<4;nt++){
        short8 bfr = *(const short8*)(w1t + (size_t)(c0+nt*16+lo16)*128 + ks*32 + quad*8);
        acc1[nt] = __builtin_amdgcn_mfma_f32_16x16x32_bf16(a1[ks], bfr, acc1[nt], 0,0,0);
      }
    __syncthreads();   // prior chunk's GEMM2 reads of ts are done
    #pragma unroll
    for (int nt=0;nt<4;nt++){
      float bb = b1[c0 + nt*16 + lo16];
      #pragma unroll
      for (int r=0;r<4;r++)
        ts[(wave*16 + quad*4 + r)*72 + nt*16 + lo16] = f2b(gelu_f(acc1[nt][r] + bb));
    }
    __syncthreads();
    // GEMM2: acc2 += t @ w2[c0:c0+64, :]
    #pragma unroll
    for (int ks2=0;ks2<2;ks2++){
      short8 a2 = *(const short8*)(&ts[(wave*16+lo16)*72 + ks2*32 + quad*8]);
      #pragma unroll
      for (int nt2=0;nt2<8;nt2++){
        short8 bfr2 = *(const short8*)(w2t + (size_t)(nt2*16+lo16)*512 + c0 + ks2*32 + quad*8);
        acc2[nt2] = __builtin_amdgcn_mfma_f32_16x16x32_bf16(a2, bfr2, acc2[nt2], 0,0,0);
      }
    }
  }
  #pragma unroll
  for (int nt=0;nt<8;nt++){
    int col = nt*16 + lo16;
    float bb = b2[col];
    #pragma unroll
    for (int r=0;r<4;r++){
      int row = mw + quad*4 + r;
      float v = acc2[nt][r] + bb + RES[(size_t)row*128 + col];
      OUT[(size_t)row*128 + col] = v;
    }
  }
}

extern "C" void kernel_launch(void* const* d_in, const int* in_sizes, int n_in,
                              void* d_out, int out_size, void* d_ws, size_t ws_size,
                              hipStream_t stream)
{
  const float* x    = (const float*)d_in[0];
  const float* ln1g = (const float*)d_in[1];
  const float* ln1b = (const float*)d_in[2];
  const float* inw  = (const float*)d_in[3];
  const float* inb  = (const float*)d_in[4];
  const float* dwk  = (const float*)d_in[5];
  const float* dwb  = (const float*)d_in[6];
  const float* dwlng= (const float*)d_in[7];
  const float* dwlnb= (const float*)d_in[8];
  const float* offw = (const float*)d_in[9];
  const float* offb = (const float*)d_in[10];
  const float* maskw= (const float*)d_in[11];
  const float* maskb= (const float*)d_in[12];
  const float* outw = (const float*)d_in[13];
  const float* outb = (const float*)d_in[14];
  const float* ln2g = (const float*)d_in[15];
  const float* ln2b = (const float*)d_in[16];
  const float* fc1w = (const float*)d_in[17];
  const float* fc1b = (const float*)d_in[18];
  const float* fc2w = (const float*)d_in[19];
  const float* fc2b = (const float*)d_in[20];
  float* out = (float*)d_out;

  bf16* ws = (bf16*)d_ws;
  const size_t S = (size_t)NHW*CC;
  // ws: R0 [0,S): xn->y | R1 [S,2S): xp->h0 | R2 [2S,3S): x1 | [3S,+320KB): Wt
  bf16* xn = ws;
  bf16* xp = ws + S;
  bf16* x1 = ws + 2*S;
  bf16* y  = xn;
  float* x2 = out;
  bf16* h0 = xp;
  bf16* inwt  = ws + 3*S;            // 128*128
  bf16* outwt = inwt + 128*128;      // 128*128
  bf16* w1t   = outwt + 128*128;     // 512*128
  bf16* w2t   = w1t + 512*128;       // 128*512

  // 0. pre-transpose weights to bf16 [n][k]
  tr_k<<<64, 256, 0, stream>>>(inw,  inwt, 7, 128, 128*128);
  tr_k<<<64, 256, 0, stream>>>(outw, outwt,7, 128, 128*128);
  tr_k<<<256,256, 0, stream>>>(fc1w, w1t,  7, 512, 512*128);
  tr_k<<<256,256, 0, stream>>>(fc2w, w2t,  9, 128, 128*512);
  // 1. xn = LN1(x)
  ln_k<<<NHW/4, 256, 0, stream>>>(x, ln1g, ln1b, xn);
  // 2. xp = xn @ in_w + in_b   [MFMA]
  gemm_mfma<bf16,false><<<dim3(2,512), 256, 0, stream>>>(xn, inwt, inb, nullptr, xp);
  // 3. x1 = gelu(LN(dwconv(xn)))
  convln_k<<<NHW, 128, 0, stream>>>(xn, dwk, dwb, dwlng, dwlnb, x1);
  // 4. y = dcn_core(xp, offset(x1), mask(x1))
  samp_k<<<NHW/64, 256, 0, stream>>>(x1, xp, offw, offb, maskw, maskb, y);
  // 5. x2 = x + (y @ out_w + out_b)   [MFMA, f32 into d_out]
  gemm_mfma<float,true><<<dim3(2,512), 256, 0, stream>>>(y, outwt, outb, x, x2);
  // 6. h0 = LN2(x2)
  ln_k<<<NHW/4, 256, 0, stream>>>(x2, ln2g, ln2b, h0);
  // 7. out = x2 + gelu(h0 @ fc1 + b1) @ fc2 + b2   [fused MFMA MLP]
  mlp_mfma<<<NHW/64, 256, 0, stream>>>(h0, w1t, fc1b, w2t, fc2b, x2, out);
}

// Round 6
// 498.578 us; speedup vs baseline: 1.9445x; 1.1737x over previous
//
#include <hip/hip_runtime.h>
#include <hip/hip_bf16.h>
#include <math.h>

#define NB 4
#define HH 128
#define WW 128
#define CC 128
#define GG 8
#define GCC 16
#define KK 9
#define NHW (NB*HH*WW)   // 65536

typedef __hip_bfloat16 bf16;
typedef __attribute__((ext_vector_type(8))) short short8;
typedef __attribute__((ext_vector_type(4))) float f32x4;

__device__ __forceinline__ float b2f(bf16 v){ return __bfloat162float(v); }
__device__ __forceinline__ bf16 f2b(float v){ return __float2bfloat16(v); }
__device__ __forceinline__ float gelu_f(float v){ return 0.5f*v*(1.f+erff(v*0.70710678118654752f)); }
__device__ __forceinline__ float lo_bf(unsigned u){ union{unsigned i; float f;} c; c.i = u<<16; return c.f; }
__device__ __forceinline__ float hi_bf(unsigned u){ union{unsigned i; float f;} c; c.i = u&0xffff0000u; return c.f; }
__device__ __forceinline__ unsigned pk(float a, float b){
  return ((unsigned)__bfloat16_as_ushort(f2b(b))<<16) | (unsigned)__bfloat16_as_ushort(f2b(a));
}
__device__ __forceinline__ void st_out(bf16* p, float v){ *p = f2b(v); }
__device__ __forceinline__ void st_out(float* p, float v){ *p = v; }

// -------- weight transpose + bf16 cvt: Wt[n*K+k] = W[k*N+n] --------
__global__ __launch_bounds__(256) void tr_k(const float* __restrict__ W,
    bf16* __restrict__ Wt, int kshift, int N, int total)
{
  int idx = blockIdx.x*256 + threadIdx.x;
  if (idx >= total) return;
  int n = idx >> kshift;
  int k = idx & ((1<<kshift)-1);
  Wt[idx] = f2b(W[(size_t)k*N + n]);
}

// ---- pack combined DCN proj weight: wsw[n*128+k] = [offw|maskw|0]^T, bf16 ----
__global__ __launch_bounds__(256) void packw_k(const float* __restrict__ offw,
    const float* __restrict__ offb, const float* __restrict__ maskw,
    const float* __restrict__ maskb, bf16* __restrict__ wsw, float* __restrict__ cw)
{
  int idx = blockIdx.x*256 + threadIdx.x;   // 224*128 = 28672
  if (idx >= 224*128) return;
  int nn = idx>>7, k = idx&127;
  float v = (nn<144) ? offw[(size_t)k*144+nn] : (nn<216 ? maskw[(size_t)k*72+(nn-144)] : 0.f);
  wsw[idx] = f2b(v);
  if (idx < 224) cw[idx] = (idx<144) ? offb[idx] : (idx<216 ? maskb[idx-144] : 0.f);
}

// ---------------- LayerNorm over C=128, one wave per pixel ----------------
__global__ __launch_bounds__(256) void ln_k(const float* __restrict__ X,
    const float* __restrict__ gam, const float* __restrict__ bet, bf16* __restrict__ Y)
{
  int lane = threadIdx.x & 63;
  int wid  = threadIdx.x >> 6;
  size_t pix = (size_t)blockIdx.x*4 + wid;
  const float* xp = X + pix*CC;
  int c0 = lane*2;
  float v0 = xp[c0], v1 = xp[c0+1];
  float s = v0+v1, ss = v0*v0+v1*v1;
  #pragma unroll
  for (int off=32; off>0; off>>=1){ s += __shfl_xor(s,off,64); ss += __shfl_xor(ss,off,64); }
  float mean = s*(1.f/CC);
  float var  = ss*(1.f/CC) - mean*mean;
  float rstd = rsqrtf(var + 1e-5f);
  float y0 = (v0-mean)*rstd*gam[c0]   + bet[c0];
  float y1 = (v1-mean)*rstd*gam[c0+1] + bet[c0+1];
  Y[pix*CC + c0]   = f2b(y0);
  Y[pix*CC + c0+1] = f2b(y1);
}

// -------- depthwise 3x3 conv + LN + GELU: 16 px x 16 ch-groups, no LDS --------
__global__ __launch_bounds__(256) void convln_k(const bf16* __restrict__ XN,
    const float* __restrict__ dwk, const float* __restrict__ dwb,
    const float* __restrict__ gam, const float* __restrict__ bet, bf16* __restrict__ X1)
{
  int tid = threadIdx.x;
  int px = tid>>4, cg = tid&15;
  int ch0 = cg*8;
  int pix = blockIdx.x*16 + px;           // 16 px stay within one row (128%16==0)
  int w = pix & (WW-1), h = (pix>>7)&(HH-1), n = pix>>14;
  float acc[8];
  {
    float4 b0 = *(const float4*)(dwb + ch0), b1 = *(const float4*)(dwb + ch0 + 4);
    acc[0]=b0.x; acc[1]=b0.y; acc[2]=b0.z; acc[3]=b0.w;
    acc[4]=b1.x; acc[5]=b1.y; acc[6]=b1.z; acc[7]=b1.w;
  }
  #pragma unroll
  for (int ky=0;ky<3;ky++){
    int yy = h+ky-1; if ((unsigned)yy>=(unsigned)HH) continue;
    #pragma unroll
    for (int kx=0;kx<3;kx++){
      int xx = w+kx-1; if ((unsigned)xx>=(unsigned)WW) continue;
      uint4 u = *(const uint4*)(XN + ((size_t)((n*HH+yy)*WW+xx))*CC + ch0);
      const float* wp = dwk + (ky*3+kx)*CC + ch0;
      float4 w0 = *(const float4*)wp; float4 w1 = *(const float4*)(wp+4);
      acc[0] += lo_bf(u.x)*w0.x; acc[1] += hi_bf(u.x)*w0.y;
      acc[2] += lo_bf(u.y)*w0.z; acc[3] += hi_bf(u.y)*w0.w;
      acc[4] += lo_bf(u.z)*w1.x; acc[5] += hi_bf(u.z)*w1.y;
      acc[6] += lo_bf(u.w)*w1.z; acc[7] += hi_bf(u.w)*w1.w;
    }
  }
  float s=0.f, ss=0.f;
  #pragma unroll
  for (int i=0;i<8;i++){ s += acc[i]; ss += acc[i]*acc[i]; }
  #pragma unroll
  for (int off=1; off<16; off<<=1){ s += __shfl_xor(s,off,64); ss += __shfl_xor(ss,off,64); }
  float mean=s*(1.f/CC), var=ss*(1.f/CC)-mean*mean, rstd=rsqrtf(var+1e-5f);
  float4 g0 = *(const float4*)(gam + ch0), g1 = *(const float4*)(gam + ch0 + 4);
  float4 be0 = *(const float4*)(bet + ch0), be1 = *(const float4*)(bet + ch0 + 4);
  float gv[8] = {g0.x,g0.y,g0.z,g0.w,g1.x,g1.y,g1.z,g1.w};
  float bv[8] = {be0.x,be0.y,be0.z,be0.w,be1.x,be1.y,be1.z,be1.w};
  float o[8];
  #pragma unroll
  for (int i=0;i<8;i++) o[i] = gelu_f((acc[i]-mean)*rstd*gv[i] + bv[i]);
  uint4 up; up.x = pk(o[0],o[1]); up.y = pk(o[2],o[3]); up.z = pk(o[4],o[5]); up.w = pk(o[6],o[7]);
  *(uint4*)(X1 + (size_t)pix*CC + ch0) = up;
}

// ---- fused DCN: MFMA projection + softmax + bilinear sampling, 32 px/block ----
#define OMS 226   // oms row stride (bf16): 113 dwords, odd -> banks spread
__global__ __launch_bounds__(256) void samp_k(const bf16* __restrict__ X1,
    const bf16* __restrict__ XP,
    const bf16* __restrict__ wsw, const float* __restrict__ cw,
    bf16* __restrict__ Y)
{
  __shared__ bf16 oms[32*OMS];   // 14464 B
  int tid = threadIdx.x;
  int pix0 = blockIdx.x*32;      // 32 px within one row segment
  int wave = tid>>6, l = tid&63, lo16 = l&15, quad = l>>4;
  // ---- phase 1: scores(32x224) = x1[pix0:pix0+32] @ wsw^T + cw, MFMA ----
  // wave w covers n-tiles w*4 .. w*4+ntn-1 (wave3: 2 tiles), both m-tiles.
  int nt0 = wave*4;
  int ntn = (wave==3) ? 2 : 4;
  short8 af[2][4];
  #pragma unroll
  for (int mt=0;mt<2;mt++)
    #pragma unroll
    for (int ks=0;ks<4;ks++)
      af[mt][ks] = *(const short8*)(X1 + (size_t)(pix0+mt*16+lo16)*128 + ks*32 + quad*8);
  f32x4 z = {0.f,0.f,0.f,0.f};
  f32x4 acc[2][4];
  #pragma unroll
  for (int mt=0;mt<2;mt++)
    #pragma unroll
    for (int t=0;t<4;t++) acc[mt][t]=z;
  for (int t=0;t<ntn;t++){
    int nt = nt0+t;
    #pragma unroll
    for (int ks=0;ks<4;ks++){
      short8 bfr = *(const short8*)(wsw + (size_t)(nt*16+lo16)*128 + ks*32 + quad*8);
      acc[0][t] = __builtin_amdgcn_mfma_f32_16x16x32_bf16(af[0][ks], bfr, acc[0][t], 0,0,0);
      acc[1][t] = __builtin_amdgcn_mfma_f32_16x16x32_bf16(af[1][ks], bfr, acc[1][t], 0,0,0);
    }
  }
  for (int t=0;t<ntn;t++){
    int col = (nt0+t)*16 + lo16;
    float bb = cw[col];
    #pragma unroll
    for (int mt=0;mt<2;mt++)
      #pragma unroll
      for (int r=0;r<4;r++)
        oms[(mt*16 + quad*4 + r)*OMS + col] = f2b(acc[mt][t][r] + bb);
  }
  __syncthreads();
  // ---- phase 2: softmax, task = (px, group), 32*8 = 256 ----
  {
    int m = tid>>3, g = tid&7;
    int base = m*OMS + 144 + g*9;
    float sc[9]; float mx = -1e30f;
    #pragma unroll
    for (int k=0;k<9;k++){ sc[k] = b2f(oms[base+k]); mx = fmaxf(mx, sc[k]); }
    float sum = 0.f;
    #pragma unroll
    for (int k=0;k<9;k++){ sc[k] = expf(sc[k]-mx); sum += sc[k]; }
    float inv = 1.f/sum;
    #pragma unroll
    for (int k=0;k<9;k++) oms[base+k] = f2b(sc[k]*inv);
  }
  __syncthreads();
  // ---- phase 3: sampling; thread = ch-quad (0..31) x slot (0..7), 4 px iters ----
  int qd = tid>>3, s = tid&7;
  int g = qd>>2;
  int ch = g*GCC + (qd&3)*4;
  int w0 = pix0 & (WW-1);
  int h  = (pix0>>7) & (HH-1);
  int n  = pix0>>14;
  const bf16* xpn = XP + (size_t)n*HH*WW*CC;
  for (int it=0; it<4; it++){
    int m = it*8 + s;
    int wc = w0 + m;
    const bf16* omrow = &oms[m*OMS];
    float a0=0.f, a1=0.f, a2=0.f, a3=0.f;
    #pragma unroll
    for (int k=0;k<9;k++){
      float offx = b2f(omrow[g*18 + 2*k]);
      float offy = b2f(omrow[g*18 + 2*k + 1]);
      float mk   = b2f(omrow[144 + g*9 + k]);
      float pxf = (float)(wc + (k/3) - 1) + offx;   // x-major grid
      float pyf = (float)(h  + (k%3) - 1) + offy;
      float x0f = floorf(pxf), y0f = floorf(pyf);
      float txf = pxf-x0f,     tyf = pyf-y0f;
      int x0 = (int)x0f, y0 = (int)y0f;
      int x1i = x0+1,    y1i = y0+1;
      float w00=(1.f-tyf)*(1.f-txf)*mk, w01=(1.f-tyf)*txf*mk;
      float w10=tyf*(1.f-txf)*mk,       w11=tyf*txf*mk;
      bool vx0=((unsigned)x0<(unsigned)WW), vx1=((unsigned)x1i<(unsigned)WW);
      bool vy0=((unsigned)y0<(unsigned)HH), vy1=((unsigned)y1i<(unsigned)HH);
      if (vy0){
        const bf16* rowp = xpn + ((size_t)y0*WW)*CC + ch;
        if (vx0){ uint2 u = *(const uint2*)(rowp + (size_t)x0*CC);
          a0 += w00*lo_bf(u.x); a1 += w00*hi_bf(u.x); a2 += w00*lo_bf(u.y); a3 += w00*hi_bf(u.y); }
        if (vx1){ uint2 u = *(const uint2*)(rowp + (size_t)x1i*CC);
          a0 += w01*lo_bf(u.x); a1 += w01*hi_bf(u.x); a2 += w01*lo_bf(u.y); a3 += w01*hi_bf(u.y); }
      }
      if (vy1){
        const bf16* rowp = xpn + ((size_t)y1i*WW)*CC + ch;
        if (vx0){ uint2 u = *(const uint2*)(rowp + (size_t)x0*CC);
          a0 += w10*lo_bf(u.x); a1 += w10*hi_bf(u.x); a2 += w10*lo_bf(u.y); a3 += w10*hi_bf(u.y); }
        if (vx1){ uint2 u = *(const uint2*)(rowp + (size_t)x1i*CC);
          a0 += w11*lo_bf(u.x); a1 += w11*hi_bf(u.x); a2 += w11*lo_bf(u.y); a3 += w11*hi_bf(u.y); }
      }
    }
    uint2 outp; outp.x = pk(a0,a1); outp.y = pk(a2,a3);
    *(uint2*)(Y + (size_t)(pix0+m)*CC + ch) = outp;
  }
}

// ------------- MFMA GEMM: C(Mx128) = A(Mx128 bf16) @ Bt^T + bias (+res) -------------
template<typename OutT, bool RES>
__global__ __launch_bounds__(256) void gemm_mfma(const bf16* __restrict__ A,
    const bf16* __restrict__ Bt, const float* __restrict__ bias,
    const float* __restrict__ res, OutT* __restrict__ C)
{
  int tid = threadIdx.x;
  int wave = tid>>6, l = tid&63, lo16 = l&15, quad = l>>4;
  int m0 = blockIdx.y*128 + wave*32;
  int n0 = blockIdx.x*64;
  short8 bfr[4][4];   // [kstep][ntile]
  #pragma unroll
  for (int ks=0;ks<4;ks++)
    #pragma unroll
    for (int nt=0;nt<4;nt++)
      bfr[ks][nt] = *(const short8*)(Bt + (size_t)(n0+nt*16+lo16)*128 + ks*32 + quad*8);
  f32x4 z = {0.f,0.f,0.f,0.f};
  f32x4 acc[2][4];
  #pragma unroll
  for (int mt=0;mt<2;mt++)
    #pragma unroll
    for (int nt=0;nt<4;nt++) acc[mt][nt]=z;
  #pragma unroll
  for (int ks=0;ks<4;ks++){
    short8 af0 = *(const short8*)(A + (size_t)(m0+lo16)*128    + ks*32 + quad*8);
    short8 af1 = *(const short8*)(A + (size_t)(m0+16+lo16)*128 + ks*32 + quad*8);
    #pragma unroll
    for (int nt=0;nt<4;nt++){
      acc[0][nt] = __builtin_amdgcn_mfma_f32_16x16x32_bf16(af0, bfr[ks][nt], acc[0][nt], 0,0,0);
      acc[1][nt] = __builtin_amdgcn_mfma_f32_16x16x32_bf16(af1, bfr[ks][nt], acc[1][nt], 0,0,0);
    }
  }
  #pragma unroll
  for (int mt=0;mt<2;mt++)
    #pragma unroll
    for (int nt=0;nt<4;nt++){
      int col = n0 + nt*16 + lo16;
      float bb = bias[col];
      #pragma unroll
      for (int r=0;r<4;r++){
        int row = m0 + mt*16 + quad*4 + r;
        float v = acc[mt][nt][r] + bb;
        if (RES) v += res[(size_t)row*128 + col];
        st_out(&C[(size_t)row*128 + col], v);
      }
    }
}

// ---- fused MFMA MLP: out = gelu(h0@fc1+b1)@fc2 + b2 + res, chunked over 512 ----
__global__ __launch_bounds__(256) void mlp_mfma(const bf16* __restrict__ H0,
    const bf16* __restrict__ w1t, const float* __restrict__ b1,
    const bf16* __restrict__ w2t, const float* __restrict__ b2,
    const float* __restrict__ RES, float* __restrict__ OUT)
{
  __shared__ bf16 ts[64*72];
  int tid = threadIdx.x;
  int wave = tid>>6, l = tid&63, lo16 = l&15, quad = l>>4;
  int m0 = blockIdx.x*64;
  int mw = m0 + wave*16;
  short8 a1[4];
  #pragma unroll
  for (int ks=0;ks<4;ks++)
    a1[ks] = *(const short8*)(H0 + (size_t)(mw+lo16)*128 + ks*32 + quad*8);
  f32x4 z = {0.f,0.f,0.f,0.f};
  f32x4 acc2[8];
  #pragma unroll
  for (int nt=0;nt<8;nt++) acc2[nt]=z;

  for (int c0=0;c0<512;c0+=64){
    f32x4 acc1[4];
    #pragma unroll
    for (int nt=0;nt<4;nt++) acc1[nt]=z;
    #pragma unroll
    for (int ks=0;ks<4;ks++)
      #pragma unroll
      for (int nt=0;nt<4;nt++){
        short8 bfr = *(const short8*)(w1t + (size_t)(c0+nt*16+lo16)*128 + ks*32 + quad*8);
        acc1[nt] = __builtin_amdgcn_mfma_f32_16x16x32_bf16(a1[ks], bfr, acc1[nt], 0,0,0);
      }
    __syncthreads();
    #pragma unroll
    for (int nt=0;nt<4;nt++){
      float bb = b1[c0 + nt*16 + lo16];
      #pragma unroll
      for (int r=0;r<4;r++)
        ts[(wave*16 + quad*4 + r)*72 + nt*16 + lo16] = f2b(gelu_f(acc1[nt][r] + bb));
    }
    __syncthreads();
    #pragma unroll
    for (int ks2=0;ks2<2;ks2++){
      short8 a2 = *(const short8*)(&ts[(wave*16+lo16)*72 + ks2*32 + quad*8]);
      #pragma unroll
      for (int nt2=0;nt2<8;nt2++){
        short8 bfr2 = *(const short8*)(w2t + (size_t)(nt2*16+lo16)*512 + c0 + ks2*32 + quad*8);
        acc2[nt2] = __builtin_amdgcn_mfma_f32_16x16x32_bf16(a2, bfr2, acc2[nt2], 0,0,0);
      }
    }
  }
  #pragma unroll
  for (int nt=0;nt<8;nt++){
    int col = nt*16 + lo16;
    float bb = b2[col];
    #pragma unroll
    for (int r=0;r<4;r++){
      int row = mw + quad*4 + r;
      float v = acc2[nt][r] + bb + RES[(size_t)row*128 + col];
      OUT[(size_t)row*128 + col] = v;
    }
  }
}

extern "C" void kernel_launch(void* const* d_in, const int* in_sizes, int n_in,
                              void* d_out, int out_size, void* d_ws, size_t ws_size,
                              hipStream_t stream)
{
  const float* x    = (const float*)d_in[0];
  const float* ln1g = (const float*)d_in[1];
  const float* ln1b = (const float*)d_in[2];
  const float* inw  = (const float*)d_in[3];
  const float* inb  = (const float*)d_in[4];
  const float* dwk  = (const float*)d_in[5];
  const float* dwb  = (const float*)d_in[6];
  const float* dwlng= (const float*)d_in[7];
  const float* dwlnb= (const float*)d_in[8];
  const float* offw = (const float*)d_in[9];
  const float* offb = (const float*)d_in[10];
  const float* maskw= (const float*)d_in[11];
  const float* maskb= (const float*)d_in[12];
  const float* outw = (const float*)d_in[13];
  const float* outb = (const float*)d_in[14];
  const float* ln2g = (const float*)d_in[15];
  const float* ln2b = (const float*)d_in[16];
  const float* fc1w = (const float*)d_in[17];
  const float* fc1b = (const float*)d_in[18];
  const float* fc2w = (const float*)d_in[19];
  const float* fc2b = (const float*)d_in[20];
  float* out = (float*)d_out;

  bf16* ws = (bf16*)d_ws;
  const size_t S = (size_t)NHW*CC;
  // ws: R0 [0,S): xn->y | R1 [S,2S): xp->h0 | R2 [2S,3S): x1 | [3S,..): weights
  bf16* xn = ws;
  bf16* xp = ws + S;
  bf16* x1 = ws + 2*S;
  bf16* y  = xn;
  float* x2 = out;
  bf16* h0 = xp;
  bf16* inwt  = ws + 3*S;            // 128*128
  bf16* outwt = inwt + 128*128;      // 128*128
  bf16* w1t   = outwt + 128*128;     // 512*128
  bf16* w2t   = w1t + 512*128;       // 128*512
  bf16* wsw   = w2t + 128*512;       // 224*128 (16B-aligned offset)
  float* cw   = (float*)(wsw + 224*128);  // 224 f32

  // 0. pre-pack weights (bf16, [n][k])
  tr_k<<<64, 256, 0, stream>>>(inw,  inwt, 7, 128, 128*128);
  tr_k<<<64, 256, 0, stream>>>(outw, outwt,7, 128, 128*128);
  tr_k<<<256,256, 0, stream>>>(fc1w, w1t,  7, 512, 512*128);
  tr_k<<<256,256, 0, stream>>>(fc2w, w2t,  9, 128, 128*512);
  packw_k<<<112,256, 0, stream>>>(offw, offb, maskw, maskb, wsw, cw);
  // 1. xn = LN1(x)
  ln_k<<<NHW/4, 256, 0, stream>>>(x, ln1g, ln1b, xn);
  // 2. xp = xn @ in_w + in_b   [MFMA]
  gemm_mfma<bf16,false><<<dim3(2,512), 256, 0, stream>>>(xn, inwt, inb, nullptr, xp);
  // 3. x1 = gelu(LN(dwconv(xn)))   [vectorized, no barriers]
  convln_k<<<NHW/16, 256, 0, stream>>>(xn, dwk, dwb, dwlng, dwlnb, x1);
  // 4. y = dcn_core(xp, offset(x1), mask(x1))   [MFMA proj + sampling]
  samp_k<<<NHW/32, 256, 0, stream>>>(x1, xp, wsw, cw, y);
  // 5. x2 = x + (y @ out_w + out_b)   [MFMA, f32 into d_out]
  gemm_mfma<float,true><<<dim3(2,512), 256, 0, stream>>>(y, outwt, outb, x, x2);
  // 6. h0 = LN2(x2)
  ln_k<<<NHW/4, 256, 0, stream>>>(x2, ln2g, ln2b, h0);
  // 7. out = x2 + gelu(h0 @ fc1 + b1) @ fc2 + b2   [fused MFMA MLP]
  mlp_mfma<<<NHW/64, 256, 0, stream>>>(h0, w1t, fc1b, w2t, fc2b, x2, out);
}

// Round 7
// 432.392 us; speedup vs baseline: 2.2422x; 1.1531x over previous
//
#include <hip/hip_runtime.h>
#include <hip/hip_bf16.h>
#include <math.h>

#define NB 4
#define HH 128
#define WW 128
#define CC 128
#define GG 8
#define GCC 16
#define KK 9
#define NHW (NB*HH*WW)   // 65536

typedef __hip_bfloat16 bf16;
typedef __attribute__((ext_vector_type(8))) short short8;
typedef __attribute__((ext_vector_type(4))) float f32x4;

__device__ __forceinline__ float b2f(bf16 v){ return __bfloat162float(v); }
__device__ __forceinline__ bf16 f2b(float v){ return __float2bfloat16(v); }
__device__ __forceinline__ float gelu_f(float v){ return 0.5f*v*(1.f+erff(v*0.70710678118654752f)); }
__device__ __forceinline__ float lo_bf(unsigned u){ union{unsigned i; float f;} c; c.i = u<<16; return c.f; }
__device__ __forceinline__ float hi_bf(unsigned u){ union{unsigned i; float f;} c; c.i = u&0xffff0000u; return c.f; }
__device__ __forceinline__ unsigned pk(float a, float b){
  return ((unsigned)__bfloat16_as_ushort(f2b(b))<<16) | (unsigned)__bfloat16_as_ushort(f2b(a));
}
__device__ __forceinline__ void st_out(bf16* p, float v){ *p = f2b(v); }
__device__ __forceinline__ void st_out(float* p, float v){ *p = v; }

// -------- weight transpose + bf16 cvt: Wt[n*K+k] = W[k*N+n] --------
__global__ __launch_bounds__(256) void tr_k(const float* __restrict__ W,
    bf16* __restrict__ Wt, int kshift, int N, int total)
{
  int idx = blockIdx.x*256 + threadIdx.x;
  if (idx >= total) return;
  int n = idx >> kshift;
  int k = idx & ((1<<kshift)-1);
  Wt[idx] = f2b(W[(size_t)k*N + n]);
}

// ---- pack combined DCN proj weight: wsw[n*128+k] = [offw|maskw|0]^T, bf16 ----
__global__ __launch_bounds__(256) void packw_k(const float* __restrict__ offw,
    const float* __restrict__ offb, const float* __restrict__ maskw,
    const float* __restrict__ maskb, bf16* __restrict__ wsw, float* __restrict__ cw)
{
  int idx = blockIdx.x*256 + threadIdx.x;   // 224*128 = 28672
  if (idx >= 224*128) return;
  int nn = idx>>7, k = idx&127;
  float v = (nn<144) ? offw[(size_t)k*144+nn] : (nn<216 ? maskw[(size_t)k*72+(nn-144)] : 0.f);
  wsw[idx] = f2b(v);
  if (idx < 224) cw[idx] = (idx<144) ? offb[idx] : (idx<216 ? maskb[idx-144] : 0.f);
}

// ---------------- LayerNorm over C=128, one wave per pixel ----------------
__global__ __launch_bounds__(256) void ln_k(const float* __restrict__ X,
    const float* __restrict__ gam, const float* __restrict__ bet, bf16* __restrict__ Y)
{
  int lane = threadIdx.x & 63;
  int wid  = threadIdx.x >> 6;
  size_t pix = (size_t)blockIdx.x*4 + wid;
  const float* xp = X + pix*CC;
  int c0 = lane*2;
  float v0 = xp[c0], v1 = xp[c0+1];
  float s = v0+v1, ss = v0*v0+v1*v1;
  #pragma unroll
  for (int off=32; off>0; off>>=1){ s += __shfl_xor(s,off,64); ss += __shfl_xor(ss,off,64); }
  float mean = s*(1.f/CC);
  float var  = ss*(1.f/CC) - mean*mean;
  float rstd = rsqrtf(var + 1e-5f);
  float y0 = (v0-mean)*rstd*gam[c0]   + bet[c0];
  float y1 = (v1-mean)*rstd*gam[c0+1] + bet[c0+1];
  Y[pix*CC + c0]   = f2b(y0);
  Y[pix*CC + c0+1] = f2b(y1);
}

// -------- depthwise 3x3 conv + LN + GELU: 16 px x 16 ch-groups, no LDS --------
__global__ __launch_bounds__(256) void convln_k(const bf16* __restrict__ XN,
    const float* __restrict__ dwk, const float* __restrict__ dwb,
    const float* __restrict__ gam, const float* __restrict__ bet, bf16* __restrict__ X1)
{
  int tid = threadIdx.x;
  int px = tid>>4, cg = tid&15;
  int ch0 = cg*8;
  int pix = blockIdx.x*16 + px;           // 16 px stay within one row (128%16==0)
  int w = pix & (WW-1), h = (pix>>7)&(HH-1), n = pix>>14;
  float acc[8];
  {
    float4 b0 = *(const float4*)(dwb + ch0), b1 = *(const float4*)(dwb + ch0 + 4);
    acc[0]=b0.x; acc[1]=b0.y; acc[2]=b0.z; acc[3]=b0.w;
    acc[4]=b1.x; acc[5]=b1.y; acc[6]=b1.z; acc[7]=b1.w;
  }
  #pragma unroll
  for (int ky=0;ky<3;ky++){
    int yy = h+ky-1; if ((unsigned)yy>=(unsigned)HH) continue;
    #pragma unroll
    for (int kx=0;kx<3;kx++){
      int xx = w+kx-1; if ((unsigned)xx>=(unsigned)WW) continue;
      uint4 u = *(const uint4*)(XN + ((size_t)((n*HH+yy)*WW+xx))*CC + ch0);
      const float* wp = dwk + (ky*3+kx)*CC + ch0;
      float4 w0 = *(const float4*)wp; float4 w1 = *(const float4*)(wp+4);
      acc[0] += lo_bf(u.x)*w0.x; acc[1] += hi_bf(u.x)*w0.y;
      acc[2] += lo_bf(u.y)*w0.z; acc[3] += hi_bf(u.y)*w0.w;
      acc[4] += lo_bf(u.z)*w1.x; acc[5] += hi_bf(u.z)*w1.y;
      acc[6] += lo_bf(u.w)*w1.z; acc[7] += hi_bf(u.w)*w1.w;
    }
  }
  float s=0.f, ss=0.f;
  #pragma unroll
  for (int i=0;i<8;i++){ s += acc[i]; ss += acc[i]*acc[i]; }
  #pragma unroll
  for (int off=1; off<16; off<<=1){ s += __shfl_xor(s,off,64); ss += __shfl_xor(ss,off,64); }
  float mean=s*(1.f/CC), var=ss*(1.f/CC)-mean*mean, rstd=rsqrtf(var+1e-5f);
  float4 g0 = *(const float4*)(gam + ch0), g1 = *(const float4*)(gam + ch0 + 4);
  float4 be0 = *(const float4*)(bet + ch0), be1 = *(const float4*)(bet + ch0 + 4);
  float gv[8] = {g0.x,g0.y,g0.z,g0.w,g1.x,g1.y,g1.z,g1.w};
  float bv[8] = {be0.x,be0.y,be0.z,be0.w,be1.x,be1.y,be1.z,be1.w};
  float o[8];
  #pragma unroll
  for (int i=0;i<8;i++) o[i] = gelu_f((acc[i]-mean)*rstd*gv[i] + bv[i]);
  uint4 up; up.x = pk(o[0],o[1]); up.y = pk(o[2],o[3]); up.z = pk(o[4],o[5]); up.w = pk(o[6],o[7]);
  *(uint4*)(X1 + (size_t)pix*CC + ch0) = up;
}

// ---- fused DCN: MFMA projection + softmax + bilinear sampling, 32 px/block ----
#define OMS 226   // oms row stride (bf16): 113 dwords, odd -> banks spread
__global__ __launch_bounds__(256) void samp_k(const bf16* __restrict__ X1,
    const bf16* __restrict__ XP,
    const bf16* __restrict__ wsw, const float* __restrict__ cw,
    bf16* __restrict__ Y)
{
  __shared__ bf16 oms[32*OMS];   // 14464 B
  int tid = threadIdx.x;
  int pix0 = blockIdx.x*32;      // 32 px within one row segment
  int wave = tid>>6, l = tid&63, lo16 = l&15, quad = l>>4;
  // ---- phase 1: scores(32x224) = x1[pix0:pix0+32] @ wsw^T + cw, MFMA ----
  int nt0 = wave*4;
  int ntn = (wave==3) ? 2 : 4;
  short8 af[2][4];
  #pragma unroll
  for (int mt=0;mt<2;mt++)
    #pragma unroll
    for (int ks=0;ks<4;ks++)
      af[mt][ks] = *(const short8*)(X1 + (size_t)(pix0+mt*16+lo16)*128 + ks*32 + quad*8);
  f32x4 z = {0.f,0.f,0.f,0.f};
  f32x4 acc[2][4];
  #pragma unroll
  for (int mt=0;mt<2;mt++)
    #pragma unroll
    for (int t=0;t<4;t++) acc[mt][t]=z;
  for (int t=0;t<ntn;t++){
    int nt = nt0+t;
    #pragma unroll
    for (int ks=0;ks<4;ks++){
      short8 bfr = *(const short8*)(wsw + (size_t)(nt*16+lo16)*128 + ks*32 + quad*8);
      acc[0][t] = __builtin_amdgcn_mfma_f32_16x16x32_bf16(af[0][ks], bfr, acc[0][t], 0,0,0);
      acc[1][t] = __builtin_amdgcn_mfma_f32_16x16x32_bf16(af[1][ks], bfr, acc[1][t], 0,0,0);
    }
  }
  for (int t=0;t<ntn;t++){
    int col = (nt0+t)*16 + lo16;
    float bb = cw[col];
    #pragma unroll
    for (int mt=0;mt<2;mt++)
      #pragma unroll
      for (int r=0;r<4;r++)
        oms[(mt*16 + quad*4 + r)*OMS + col] = f2b(acc[mt][t][r] + bb);
  }
  __syncthreads();
  // ---- phase 2: softmax, task = (px, group), 32*8 = 256 ----
  {
    int m = tid>>3, g = tid&7;
    int base = m*OMS + 144 + g*9;
    float sc[9]; float mx = -1e30f;
    #pragma unroll
    for (int k=0;k<9;k++){ sc[k] = b2f(oms[base+k]); mx = fmaxf(mx, sc[k]); }
    float sum = 0.f;
    #pragma unroll
    for (int k=0;k<9;k++){ sc[k] = expf(sc[k]-mx); sum += sc[k]; }
    float inv = 1.f/sum;
    #pragma unroll
    for (int k=0;k<9;k++) oms[base+k] = f2b(sc[k]*inv);
  }
  __syncthreads();
  // ---- phase 3: sampling; lane = ch-oct (coalesced within px), slot = tid>>4 ----
  int oct = tid&15, sl = tid>>4;
  int g = oct>>1;
  int ch = g*GCC + (oct&1)*8;
  int w0 = pix0 & (WW-1);
  int h  = (pix0>>7) & (HH-1);
  int n  = pix0>>14;
  const bf16* xpn = XP + (size_t)n*HH*WW*CC;
  for (int it=0; it<2; it++){
    int m = it*16 + sl;
    int wc = w0 + m;
    const bf16* omrow = &oms[m*OMS];
    float a[8] = {0.f,0.f,0.f,0.f,0.f,0.f,0.f,0.f};
    #pragma unroll
    for (int k=0;k<9;k++){
      float offx = b2f(omrow[g*18 + 2*k]);
      float offy = b2f(omrow[g*18 + 2*k + 1]);
      float mk   = b2f(omrow[144 + g*9 + k]);
      float pxf = (float)(wc + (k/3) - 1) + offx;   // x-major grid
      float pyf = (float)(h  + (k%3) - 1) + offy;
      float x0f = floorf(pxf), y0f = floorf(pyf);
      float txf = pxf-x0f,     tyf = pyf-y0f;
      int x0 = (int)x0f, y0 = (int)y0f;
      int x1i = x0+1,    y1i = y0+1;
      float w00=(1.f-tyf)*(1.f-txf)*mk, w01=(1.f-tyf)*txf*mk;
      float w10=tyf*(1.f-txf)*mk,       w11=tyf*txf*mk;
      bool vx0=((unsigned)x0<(unsigned)WW), vx1=((unsigned)x1i<(unsigned)WW);
      bool vy0=((unsigned)y0<(unsigned)HH), vy1=((unsigned)y1i<(unsigned)HH);
      if (vy0){
        const bf16* rowp = xpn + ((size_t)y0*WW)*CC + ch;
        if (vx0){ uint4 u = *(const uint4*)(rowp + (size_t)x0*CC);
          a[0]+=w00*lo_bf(u.x); a[1]+=w00*hi_bf(u.x); a[2]+=w00*lo_bf(u.y); a[3]+=w00*hi_bf(u.y);
          a[4]+=w00*lo_bf(u.z); a[5]+=w00*hi_bf(u.z); a[6]+=w00*lo_bf(u.w); a[7]+=w00*hi_bf(u.w); }
        if (vx1){ uint4 u = *(const uint4*)(rowp + (size_t)x1i*CC);
          a[0]+=w01*lo_bf(u.x); a[1]+=w01*hi_bf(u.x); a[2]+=w01*lo_bf(u.y); a[3]+=w01*hi_bf(u.y);
          a[4]+=w01*lo_bf(u.z); a[5]+=w01*hi_bf(u.z); a[6]+=w01*lo_bf(u.w); a[7]+=w01*hi_bf(u.w); }
      }
      if (vy1){
        const bf16* rowp = xpn + ((size_t)y1i*WW)*CC + ch;
        if (vx0){ uint4 u = *(const uint4*)(rowp + (size_t)x0*CC);
          a[0]+=w10*lo_bf(u.x); a[1]+=w10*hi_bf(u.x); a[2]+=w10*lo_bf(u.y); a[3]+=w10*hi_bf(u.y);
          a[4]+=w10*lo_bf(u.z); a[5]+=w10*hi_bf(u.z); a[6]+=w10*lo_bf(u.w); a[7]+=w10*hi_bf(u.w); }
        if (vx1){ uint4 u = *(const uint4*)(rowp + (size_t)x1i*CC);
          a[0]+=w11*lo_bf(u.x); a[1]+=w11*hi_bf(u.x); a[2]+=w11*lo_bf(u.y); a[3]+=w11*hi_bf(u.y);
          a[4]+=w11*lo_bf(u.z); a[5]+=w11*hi_bf(u.z); a[6]+=w11*lo_bf(u.w); a[7]+=w11*hi_bf(u.w); }
      }
    }
    uint4 outp;
    outp.x = pk(a[0],a[1]); outp.y = pk(a[2],a[3]);
    outp.z = pk(a[4],a[5]); outp.w = pk(a[6],a[7]);
    *(uint4*)(Y + (size_t)(pix0+m)*CC + ch) = outp;
  }
}

// ------------- MFMA GEMM: C(Mx128) = A(Mx128 bf16) @ Bt^T + bias (+res) -------------
template<typename OutT, bool RES>
__global__ __launch_bounds__(256) void gemm_mfma(const bf16* __restrict__ A,
    const bf16* __restrict__ Bt, const float* __restrict__ bias,
    const float* __restrict__ res, OutT* __restrict__ C)
{
  int tid = threadIdx.x;
  int wave = tid>>6, l = tid&63, lo16 = l&15, quad = l>>4;
  int m0 = blockIdx.y*128 + wave*32;
  int n0 = blockIdx.x*64;
  short8 bfr[4][4];   // [kstep][ntile]
  #pragma unroll
  for (int ks=0;ks<4;ks++)
    #pragma unroll
    for (int nt=0;nt<4;nt++)
      bfr[ks][nt] = *(const short8*)(Bt + (size_t)(n0+nt*16+lo16)*128 + ks*32 + quad*8);
  f32x4 z = {0.f,0.f,0.f,0.f};
  f32x4 acc[2][4];
  #pragma unroll
  for (int mt=0;mt<2;mt++)
    #pragma unroll
    for (int nt=0;nt<4;nt++) acc[mt][nt]=z;
  #pragma unroll
  for (int ks=0;ks<4;ks++){
    short8 af0 = *(const short8*)(A + (size_t)(m0+lo16)*128    + ks*32 + quad*8);
    short8 af1 = *(const short8*)(A + (size_t)(m0+16+lo16)*128 + ks*32 + quad*8);
    #pragma unroll
    for (int nt=0;nt<4;nt++){
      acc[0][nt] = __builtin_amdgcn_mfma_f32_16x16x32_bf16(af0, bfr[ks][nt], acc[0][nt], 0,0,0);
      acc[1][nt] = __builtin_amdgcn_mfma_f32_16x16x32_bf16(af1, bfr[ks][nt], acc[1][nt], 0,0,0);
    }
  }
  #pragma unroll
  for (int mt=0;mt<2;mt++)
    #pragma unroll
    for (int nt=0;nt<4;nt++){
      int col = n0 + nt*16 + lo16;
      float bb = bias[col];
      #pragma unroll
      for (int r=0;r<4;r++){
        int row = m0 + mt*16 + quad*4 + r;
        float v = acc[mt][nt][r] + bb;
        if (RES) v += res[(size_t)row*128 + col];
        st_out(&C[(size_t)row*128 + col], v);
      }
    }
}

// ---- fused MFMA MLP with internal LN2: out = x2 + gelu(LN(x2)@fc1+b1)@fc2+b2 ----
// In-place on d_out: block reads/writes only its own 64 rows, barrier-ordered.
__global__ __launch_bounds__(256) void mlp_mfma(const float* __restrict__ X2,
    const float* __restrict__ lng, const float* __restrict__ lnb,
    const bf16* __restrict__ w1t, const float* __restrict__ b1,
    const bf16* __restrict__ w2t, const float* __restrict__ b2,
    float* __restrict__ OUT)
{
  __shared__ bf16 h0s[64*136];   // 17.4 KB, stride 136: 2-way bank alias (free)
  __shared__ bf16 ts[64*72];     // 9.2 KB
  int tid = threadIdx.x;
  int wave = tid>>6, l = tid&63, lo16 = l&15, quad = l>>4;
  int m0 = blockIdx.x*64;
  // ---- LN2 on the block's 64x128 tile: thread = (px, 32-ch quarter) ----
  {
    int px = tid>>2, q = tid&3;
    const float* xr = X2 + (size_t)(m0+px)*128 + q*32;
    float v[32];
    #pragma unroll
    for (int i=0;i<8;i++) *(float4*)(v+i*4) = *(const float4*)(xr+i*4);
    float s=0.f, ss=0.f;
    #pragma unroll
    for (int i=0;i<32;i++){ s += v[i]; ss += v[i]*v[i]; }
    s  += __shfl_xor(s,1,64);  ss += __shfl_xor(ss,1,64);
    s  += __shfl_xor(s,2,64);  ss += __shfl_xor(ss,2,64);
    float mean = s*(1.f/CC), var = ss*(1.f/CC)-mean*mean, rstd = rsqrtf(var+1e-5f);
    const float* gp = lng + q*32; const float* bp = lnb + q*32;
    uint4* dst = (uint4*)(&h0s[px*136 + q*32]);
    #pragma unroll
    for (int i=0;i<4;i++){
      float4 g0 = *(const float4*)(gp+i*8),  g1 = *(const float4*)(gp+i*8+4);
      float4 c0 = *(const float4*)(bp+i*8),  c1 = *(const float4*)(bp+i*8+4);
      float o0 = (v[i*8+0]-mean)*rstd*g0.x + c0.x;
      float o1 = (v[i*8+1]-mean)*rstd*g0.y + c0.y;
      float o2 = (v[i*8+2]-mean)*rstd*g0.z + c0.z;
      float o3 = (v[i*8+3]-mean)*rstd*g0.w + c0.w;
      float o4 = (v[i*8+4]-mean)*rstd*g1.x + c1.x;
      float o5 = (v[i*8+5]-mean)*rstd*g1.y + c1.y;
      float o6 = (v[i*8+6]-mean)*rstd*g1.z + c1.z;
      float o7 = (v[i*8+7]-mean)*rstd*g1.w + c1.w;
      uint4 up; up.x = pk(o0,o1); up.y = pk(o2,o3); up.z = pk(o4,o5); up.w = pk(o6,o7);
      dst[i] = up;
    }
  }
  __syncthreads();
  int mw = m0 + wave*16;
  short8 a1[4];
  #pragma unroll
  for (int ks=0;ks<4;ks++)
    a1[ks] = *(const short8*)(&h0s[(wave*16+lo16)*136 + ks*32 + quad*8]);
  f32x4 z = {0.f,0.f,0.f,0.f};
  f32x4 acc2[8];
  #pragma unroll
  for (int nt=0;nt<8;nt++) acc2[nt]=z;

  for (int c0=0;c0<512;c0+=64){
    f32x4 acc1[4];
    #pragma unroll
    for (int nt=0;nt<4;nt++) acc1[nt]=z;
    #pragma unroll
    for (int ks=0;ks<4;ks++)
      #pragma unroll
      for (int nt=0;nt<4;nt++){
        short8 bfr = *(const short8*)(w1t + (size_t)(c0+nt*16+lo16)*128 + ks*32 + quad*8);
        acc1[nt] = __builtin_amdgcn_mfma_f32_16x16x32_bf16(a1[ks], bfr, acc1[nt], 0,0,0);
      }
    __syncthreads();
    #pragma unroll
    for (int nt=0;nt<4;nt++){
      float bb = b1[c0 + nt*16 + lo16];
      #pragma unroll
      for (int r=0;r<4;r++)
        ts[(wave*16 + quad*4 + r)*72 + nt*16 + lo16] = f2b(gelu_f(acc1[nt][r] + bb));
    }
    __syncthreads();
    #pragma unroll
    for (int ks2=0;ks2<2;ks2++){
      short8 a2 = *(const short8*)(&ts[(wave*16+lo16)*72 + ks2*32 + quad*8]);
      #pragma unroll
      for (int nt2=0;nt2<8;nt2++){
        short8 bfr2 = *(const short8*)(w2t + (size_t)(nt2*16+lo16)*512 + c0 + ks2*32 + quad*8);
        acc2[nt2] = __builtin_amdgcn_mfma_f32_16x16x32_bf16(a2, bfr2, acc2[nt2], 0,0,0);
      }
    }
  }
  #pragma unroll
  for (int nt=0;nt<8;nt++){
    int col = nt*16 + lo16;
    float bb = b2[col];
    #pragma unroll
    for (int r=0;r<4;r++){
      int row = mw + quad*4 + r;
      float v = acc2[nt][r] + bb + X2[(size_t)row*128 + col];
      OUT[(size_t)row*128 + col] = v;
    }
  }
}

extern "C" void kernel_launch(void* const* d_in, const int* in_sizes, int n_in,
                              void* d_out, int out_size, void* d_ws, size_t ws_size,
                              hipStream_t stream)
{
  const float* x    = (const float*)d_in[0];
  const float* ln1g = (const float*)d_in[1];
  const float* ln1b = (const float*)d_in[2];
  const float* inw  = (const float*)d_in[3];
  const float* inb  = (const float*)d_in[4];
  const float* dwk  = (const float*)d_in[5];
  const float* dwb  = (const float*)d_in[6];
  const float* dwlng= (const float*)d_in[7];
  const float* dwlnb= (const float*)d_in[8];
  const float* offw = (const float*)d_in[9];
  const float* offb = (const float*)d_in[10];
  const float* maskw= (const float*)d_in[11];
  const float* maskb= (const float*)d_in[12];
  const float* outw = (const float*)d_in[13];
  const float* outb = (const float*)d_in[14];
  const float* ln2g = (const float*)d_in[15];
  const float* ln2b = (const float*)d_in[16];
  const float* fc1w = (const float*)d_in[17];
  const float* fc1b = (const float*)d_in[18];
  const float* fc2w = (const float*)d_in[19];
  const float* fc2b = (const float*)d_in[20];
  float* out = (float*)d_out;

  bf16* ws = (bf16*)d_ws;
  const size_t S = (size_t)NHW*CC;
  // ws: R0 [0,S): xn->y | R1 [S,2S): xp | R2 [2S,3S): x1 | [3S,..): weights
  bf16* xn = ws;
  bf16* xp = ws + S;
  bf16* x1 = ws + 2*S;
  bf16* y  = xn;
  float* x2 = out;
  bf16* inwt  = ws + 3*S;            // 128*128
  bf16* outwt = inwt + 128*128;      // 128*128
  bf16* w1t   = outwt + 128*128;     // 512*128
  bf16* w2t   = w1t + 512*128;       // 128*512
  bf16* wsw   = w2t + 128*512;       // 224*128
  float* cw   = (float*)(wsw + 224*128);  // 224 f32

  // 0. pre-pack weights (bf16, [n][k])
  tr_k<<<64, 256, 0, stream>>>(inw,  inwt, 7, 128, 128*128);
  tr_k<<<64, 256, 0, stream>>>(outw, outwt,7, 128, 128*128);
  tr_k<<<256,256, 0, stream>>>(fc1w, w1t,  7, 512, 512*128);
  tr_k<<<256,256, 0, stream>>>(fc2w, w2t,  9, 128, 128*512);
  packw_k<<<112,256, 0, stream>>>(offw, offb, maskw, maskb, wsw, cw);
  // 1. xn = LN1(x)
  ln_k<<<NHW/4, 256, 0, stream>>>(x, ln1g, ln1b, xn);
  // 2. xp = xn @ in_w + in_b   [MFMA]
  gemm_mfma<bf16,false><<<dim3(2,512), 256, 0, stream>>>(xn, inwt, inb, nullptr, xp);
  // 3. x1 = gelu(LN(dwconv(xn)))
  convln_k<<<NHW/16, 256, 0, stream>>>(xn, dwk, dwb, dwlng, dwlnb, x1);
  // 4. y = dcn_core(xp, offset(x1), mask(x1))
  samp_k<<<NHW/32, 256, 0, stream>>>(x1, xp, wsw, cw, y);
  // 5. x2 = x + (y @ out_w + out_b)   [MFMA, f32 into d_out]
  gemm_mfma<float,true><<<dim3(2,512), 256, 0, stream>>>(y, outwt, outb, x, x2);
  // 6+7. out = x2 + gelu(LN2(x2) @ fc1 + b1) @ fc2 + b2   [fused, in-place d_out]
  mlp_mfma<<<NHW/64, 256, 0, stream>>>(x2, ln2g, ln2b, w1t, fc1b, w2t, fc2b, out);
}

// Round 8
// 304.239 us; speedup vs baseline: 3.1866x; 1.4212x over previous
//
#include <hip/hip_runtime.h>
#include <hip/hip_bf16.h>
#include <math.h>

#define NB 4
#define HH 128
#define WW 128
#define CC 128
#define GG 8
#define GCC 16
#define KK 9
#define NHW (NB*HH*WW)   // 65536

typedef __hip_bfloat16 bf16;
typedef __attribute__((ext_vector_type(8))) short short8;
typedef __attribute__((ext_vector_type(4))) float f32x4;

__device__ __forceinline__ float b2f(bf16 v){ return __bfloat162float(v); }
__device__ __forceinline__ bf16 f2b(float v){ return __float2bfloat16(v); }
__device__ __forceinline__ float gelu_f(float v){ return 0.5f*v*(1.f+erff(v*0.70710678118654752f)); }
__device__ __forceinline__ float lo_bf(unsigned u){ union{unsigned i; float f;} c; c.i = u<<16; return c.f; }
__device__ __forceinline__ float hi_bf(unsigned u){ union{unsigned i; float f;} c; c.i = u&0xffff0000u; return c.f; }
__device__ __forceinline__ unsigned pk(float a, float b){
  return ((unsigned)__bfloat16_as_ushort(f2b(b))<<16) | (unsigned)__bfloat16_as_ushort(f2b(a));
}
__device__ __forceinline__ void st_out(bf16* p, float v){ *p = f2b(v); }
__device__ __forceinline__ void st_out(float* p, float v){ *p = v; }

// -------- weight transpose + bf16 cvt: Wt[n*K+k] = W[k*N+n] --------
__global__ __launch_bounds__(256) void tr_k(const float* __restrict__ W,
    bf16* __restrict__ Wt, int kshift, int N, int total)
{
  int idx = blockIdx.x*256 + threadIdx.x;
  if (idx >= total) return;
  int n = idx >> kshift;
  int k = idx & ((1<<kshift)-1);
  Wt[idx] = f2b(W[(size_t)k*N + n]);
}

// ---- pack combined DCN proj weight: wsw[n*128+k] = [offw|maskw|0]^T, bf16 ----
__global__ __launch_bounds__(256) void packw_k(const float* __restrict__ offw,
    const float* __restrict__ offb, const float* __restrict__ maskw,
    const float* __restrict__ maskb, bf16* __restrict__ wsw, float* __restrict__ cw)
{
  int idx = blockIdx.x*256 + threadIdx.x;   // 224*128 = 28672
  if (idx >= 224*128) return;
  int nn = idx>>7, k = idx&127;
  float v = (nn<144) ? offw[(size_t)k*144+nn] : (nn<216 ? maskw[(size_t)k*72+(nn-144)] : 0.f);
  wsw[idx] = f2b(v);
  if (idx < 224) cw[idx] = (idx<144) ? offb[idx] : (idx<216 ? maskb[idx-144] : 0.f);
}

// ---------------- LayerNorm over C=128, one wave per pixel ----------------
__global__ __launch_bounds__(256) void ln_k(const float* __restrict__ X,
    const float* __restrict__ gam, const float* __restrict__ bet, bf16* __restrict__ Y)
{
  int lane = threadIdx.x & 63;
  int wid  = threadIdx.x >> 6;
  size_t pix = (size_t)blockIdx.x*4 + wid;
  const float* xp = X + pix*CC;
  int c0 = lane*2;
  float v0 = xp[c0], v1 = xp[c0+1];
  float s = v0+v1, ss = v0*v0+v1*v1;
  #pragma unroll
  for (int off=32; off>0; off>>=1){ s += __shfl_xor(s,off,64); ss += __shfl_xor(ss,off,64); }
  float mean = s*(1.f/CC);
  float var  = ss*(1.f/CC) - mean*mean;
  float rstd = rsqrtf(var + 1e-5f);
  float y0 = (v0-mean)*rstd*gam[c0]   + bet[c0];
  float y1 = (v1-mean)*rstd*gam[c0+1] + bet[c0+1];
  Y[pix*CC + c0]   = f2b(y0);
  Y[pix*CC + c0+1] = f2b(y1);
}

// -------- depthwise 3x3 conv + LN + GELU: 16 px x 16 ch-groups, no LDS --------
__global__ __launch_bounds__(256) void convln_k(const bf16* __restrict__ XN,
    const float* __restrict__ dwk, const float* __restrict__ dwb,
    const float* __restrict__ gam, const float* __restrict__ bet, bf16* __restrict__ X1)
{
  int tid = threadIdx.x;
  int px = tid>>4, cg = tid&15;
  int ch0 = cg*8;
  int pix = blockIdx.x*16 + px;           // 16 px stay within one row (128%16==0)
  int w = pix & (WW-1), h = (pix>>7)&(HH-1), n = pix>>14;
  float acc[8];
  {
    float4 b0 = *(const float4*)(dwb + ch0), b1 = *(const float4*)(dwb + ch0 + 4);
    acc[0]=b0.x; acc[1]=b0.y; acc[2]=b0.z; acc[3]=b0.w;
    acc[4]=b1.x; acc[5]=b1.y; acc[6]=b1.z; acc[7]=b1.w;
  }
  #pragma unroll
  for (int ky=0;ky<3;ky++){
    int yy = h+ky-1; if ((unsigned)yy>=(unsigned)HH) continue;
    #pragma unroll
    for (int kx=0;kx<3;kx++){
      int xx = w+kx-1; if ((unsigned)xx>=(unsigned)WW) continue;
      uint4 u = *(const uint4*)(XN + ((size_t)((n*HH+yy)*WW+xx))*CC + ch0);
      const float* wp = dwk + (ky*3+kx)*CC + ch0;
      float4 w0 = *(const float4*)wp; float4 w1 = *(const float4*)(wp+4);
      acc[0] += lo_bf(u.x)*w0.x; acc[1] += hi_bf(u.x)*w0.y;
      acc[2] += lo_bf(u.y)*w0.z; acc[3] += hi_bf(u.y)*w0.w;
      acc[4] += lo_bf(u.z)*w1.x; acc[5] += hi_bf(u.z)*w1.y;
      acc[6] += lo_bf(u.w)*w1.z; acc[7] += hi_bf(u.w)*w1.w;
    }
  }
  float s=0.f, ss=0.f;
  #pragma unroll
  for (int i=0;i<8;i++){ s += acc[i]; ss += acc[i]*acc[i]; }
  #pragma unroll
  for (int off=1; off<16; off<<=1){ s += __shfl_xor(s,off,64); ss += __shfl_xor(ss,off,64); }
  float mean=s*(1.f/CC), var=ss*(1.f/CC)-mean*mean, rstd=rsqrtf(var+1e-5f);
  float4 g0 = *(const float4*)(gam + ch0), g1 = *(const float4*)(gam + ch0 + 4);
  float4 be0 = *(const float4*)(bet + ch0), be1 = *(const float4*)(bet + ch0 + 4);
  float gv[8] = {g0.x,g0.y,g0.z,g0.w,g1.x,g1.y,g1.z,g1.w};
  float bv[8] = {be0.x,be0.y,be0.z,be0.w,be1.x,be1.y,be1.z,be1.w};
  float o[8];
  #pragma unroll
  for (int i=0;i<8;i++) o[i] = gelu_f((acc[i]-mean)*rstd*gv[i] + bv[i]);
  uint4 up; up.x = pk(o[0],o[1]); up.y = pk(o[2],o[3]); up.z = pk(o[4],o[5]); up.w = pk(o[6],o[7]);
  *(uint4*)(X1 + (size_t)pix*CC + ch0) = up;
}

// ---- fused DCN: MFMA projection + softmax + bilinear sampling, 32 px/block ----
#define OMS 226   // oms row stride (bf16): 113 dwords, odd -> banks spread
__global__ __launch_bounds__(256) void samp_k(const bf16* __restrict__ X1,
    const bf16* __restrict__ XP,
    const bf16* __restrict__ wsw, const float* __restrict__ cw,
    bf16* __restrict__ Y)
{
  __shared__ bf16 oms[32*OMS];   // 14464 B
  int tid = threadIdx.x;
  int pix0 = blockIdx.x*32;      // 32 px within one row segment
  int wave = tid>>6, l = tid&63, lo16 = l&15, quad = l>>4;
  // ---- phase 1: scores(32x224) = x1[pix0:pix0+32] @ wsw^T + cw, MFMA ----
  int nt0 = wave*4;
  int ntn = (wave==3) ? 2 : 4;
  short8 af[2][4];
  #pragma unroll
  for (int mt=0;mt<2;mt++)
    #pragma unroll
    for (int ks=0;ks<4;ks++)
      af[mt][ks] = *(const short8*)(X1 + (size_t)(pix0+mt*16+lo16)*128 + ks*32 + quad*8);
  f32x4 z = {0.f,0.f,0.f,0.f};
  f32x4 acc[2][4];
  #pragma unroll
  for (int mt=0;mt<2;mt++)
    #pragma unroll
    for (int t=0;t<4;t++) acc[mt][t]=z;
  for (int t=0;t<ntn;t++){
    int nt = nt0+t;
    #pragma unroll
    for (int ks=0;ks<4;ks++){
      short8 bfr = *(const short8*)(wsw + (size_t)(nt*16+lo16)*128 + ks*32 + quad*8);
      acc[0][t] = __builtin_amdgcn_mfma_f32_16x16x32_bf16(af[0][ks], bfr, acc[0][t], 0,0,0);
      acc[1][t] = __builtin_amdgcn_mfma_f32_16x16x32_bf16(af[1][ks], bfr, acc[1][t], 0,0,0);
    }
  }
  for (int t=0;t<ntn;t++){
    int col = (nt0+t)*16 + lo16;
    float bb = cw[col];
    #pragma unroll
    for (int mt=0;mt<2;mt++)
      #pragma unroll
      for (int r=0;r<4;r++)
        oms[(mt*16 + quad*4 + r)*OMS + col] = f2b(acc[mt][t][r] + bb);
  }
  __syncthreads();
  // ---- phase 2: softmax, task = (px, group), 32*8 = 256 ----
  {
    int m = tid>>3, g = tid&7;
    int base = m*OMS + 144 + g*9;
    float sc[9]; float mx = -1e30f;
    #pragma unroll
    for (int k=0;k<9;k++){ sc[k] = b2f(oms[base+k]); mx = fmaxf(mx, sc[k]); }
    float sum = 0.f;
    #pragma unroll
    for (int k=0;k<9;k++){ sc[k] = expf(sc[k]-mx); sum += sc[k]; }
    float inv = 1.f/sum;
    #pragma unroll
    for (int k=0;k<9;k++) oms[base+k] = f2b(sc[k]*inv);
  }
  __syncthreads();
  // ---- phase 3: sampling; lane = ch-oct (coalesced within px), slot = tid>>4 ----
  int oct = tid&15, sl = tid>>4;
  int g = oct>>1;
  int ch = g*GCC + (oct&1)*8;
  int w0 = pix0 & (WW-1);
  int h  = (pix0>>7) & (HH-1);
  int n  = pix0>>14;
  const bf16* xpn = XP + (size_t)n*HH*WW*CC;
  for (int it=0; it<2; it++){
    int m = it*16 + sl;
    int wc = w0 + m;
    const bf16* omrow = &oms[m*OMS];
    float a[8] = {0.f,0.f,0.f,0.f,0.f,0.f,0.f,0.f};
    #pragma unroll
    for (int k=0;k<9;k++){
      float offx = b2f(omrow[g*18 + 2*k]);
      float offy = b2f(omrow[g*18 + 2*k + 1]);
      float mk   = b2f(omrow[144 + g*9 + k]);
      float pxf = (float)(wc + (k/3) - 1) + offx;   // x-major grid
      float pyf = (float)(h  + (k%3) - 1) + offy;
      float x0f = floorf(pxf), y0f = floorf(pyf);
      float txf = pxf-x0f,     tyf = pyf-y0f;
      int x0 = (int)x0f, y0 = (int)y0f;
      int x1i = x0+1,    y1i = y0+1;
      float w00=(1.f-tyf)*(1.f-txf)*mk, w01=(1.f-tyf)*txf*mk;
      float w10=tyf*(1.f-txf)*mk,       w11=tyf*txf*mk;
      bool vx0=((unsigned)x0<(unsigned)WW), vx1=((unsigned)x1i<(unsigned)WW);
      bool vy0=((unsigned)y0<(unsigned)HH), vy1=((unsigned)y1i<(unsigned)HH);
      if (vy0){
        const bf16* rowp = xpn + ((size_t)y0*WW)*CC + ch;
        if (vx0){ uint4 u = *(const uint4*)(rowp + (size_t)x0*CC);
          a[0]+=w00*lo_bf(u.x); a[1]+=w00*hi_bf(u.x); a[2]+=w00*lo_bf(u.y); a[3]+=w00*hi_bf(u.y);
          a[4]+=w00*lo_bf(u.z); a[5]+=w00*hi_bf(u.z); a[6]+=w00*lo_bf(u.w); a[7]+=w00*hi_bf(u.w); }
        if (vx1){ uint4 u = *(const uint4*)(rowp + (size_t)x1i*CC);
          a[0]+=w01*lo_bf(u.x); a[1]+=w01*hi_bf(u.x); a[2]+=w01*lo_bf(u.y); a[3]+=w01*hi_bf(u.y);
          a[4]+=w01*lo_bf(u.z); a[5]+=w01*hi_bf(u.z); a[6]+=w01*lo_bf(u.w); a[7]+=w01*hi_bf(u.w); }
      }
      if (vy1){
        const bf16* rowp = xpn + ((size_t)y1i*WW)*CC + ch;
        if (vx0){ uint4 u = *(const uint4*)(rowp + (size_t)x0*CC);
          a[0]+=w10*lo_bf(u.x); a[1]+=w10*hi_bf(u.x); a[2]+=w10*lo_bf(u.y); a[3]+=w10*hi_bf(u.y);
          a[4]+=w10*lo_bf(u.z); a[5]+=w10*hi_bf(u.z); a[6]+=w10*lo_bf(u.w); a[7]+=w10*hi_bf(u.w); }
        if (vx1){ uint4 u = *(const uint4*)(rowp + (size_t)x1i*CC);
          a[0]+=w11*lo_bf(u.x); a[1]+=w11*hi_bf(u.x); a[2]+=w11*lo_bf(u.y); a[3]+=w11*hi_bf(u.y);
          a[4]+=w11*lo_bf(u.z); a[5]+=w11*hi_bf(u.z); a[6]+=w11*lo_bf(u.w); a[7]+=w11*hi_bf(u.w); }
      }
    }
    uint4 outp;
    outp.x = pk(a[0],a[1]); outp.y = pk(a[2],a[3]);
    outp.z = pk(a[4],a[5]); outp.w = pk(a[6],a[7]);
    *(uint4*)(Y + (size_t)(pix0+m)*CC + ch) = outp;
  }
}

// ------------- MFMA GEMM: C(Mx128) = A(Mx128 bf16) @ Bt^T + bias (+res) -------------
// 4 m-tiles per wave (B-frag reuse 4). Block = 256 rows, grid (2, 256).
template<typename OutT, bool RES>
__global__ __launch_bounds__(256) void gemm_mfma(const bf16* __restrict__ A,
    const bf16* __restrict__ Bt, const float* __restrict__ bias,
    const float* __restrict__ res, OutT* __restrict__ C)
{
  int tid = threadIdx.x;
  int wave = tid>>6, l = tid&63, lo16 = l&15, quad = l>>4;
  int m0 = blockIdx.y*256 + wave*64;
  int n0 = blockIdx.x*64;
  short8 bfr[4][4];   // [kstep][ntile]
  #pragma unroll
  for (int ks=0;ks<4;ks++)
    #pragma unroll
    for (int nt=0;nt<4;nt++)
      bfr[ks][nt] = *(const short8*)(Bt + (size_t)(n0+nt*16+lo16)*128 + ks*32 + quad*8);
  f32x4 z = {0.f,0.f,0.f,0.f};
  f32x4 acc[4][4];
  #pragma unroll
  for (int mt=0;mt<4;mt++)
    #pragma unroll
    for (int nt=0;nt<4;nt++) acc[mt][nt]=z;
  #pragma unroll
  for (int ks=0;ks<4;ks++){
    short8 af[4];
    #pragma unroll
    for (int mt=0;mt<4;mt++)
      af[mt] = *(const short8*)(A + (size_t)(m0+mt*16+lo16)*128 + ks*32 + quad*8);
    #pragma unroll
    for (int nt=0;nt<4;nt++)
      #pragma unroll
      for (int mt=0;mt<4;mt++)
        acc[mt][nt] = __builtin_amdgcn_mfma_f32_16x16x32_bf16(af[mt], bfr[ks][nt], acc[mt][nt], 0,0,0);
  }
  #pragma unroll
  for (int mt=0;mt<4;mt++)
    #pragma unroll
    for (int nt=0;nt<4;nt++){
      int col = n0 + nt*16 + lo16;
      float bb = bias[col];
      #pragma unroll
      for (int r=0;r<4;r++){
        int row = m0 + mt*16 + quad*4 + r;
        float v = acc[mt][nt][r] + bb;
        if (RES) v += res[(size_t)row*128 + col];
        st_out(&C[(size_t)row*128 + col], v);
      }
    }
}

// ---- fused MFMA MLP with internal LN2, LDS-staged weights, 128 px/block ----
// out = x2 + gelu(LN(x2)@fc1+b1)@fc2+b2. In-place on d_out (own rows only).
// LDS: region1 = h0s(128x136 bf16, 34816B) reused as ts(128x72); region2 =
// wstage(18432B) alternating w1-chunk(64x136)/w2-chunk(128x72).
__global__ __launch_bounds__(256) void mlp_mfma(const float* __restrict__ X2,
    const float* __restrict__ lng, const float* __restrict__ lnb,
    const bf16* __restrict__ w1t, const float* __restrict__ b1,
    const bf16* __restrict__ w2t, const float* __restrict__ b2,
    float* __restrict__ OUT)
{
  __shared__ __align__(16) char smem[34816 + 18432];
  bf16* h0s = (bf16*)smem;             // 128 x 136
  bf16* ts  = (bf16*)smem;             // 128 x 72 (aliases h0s after a1 loads)
  bf16* w1s = (bf16*)(smem + 34816);   // 64 x 136
  bf16* w2s = (bf16*)(smem + 34816);   // 128 x 72 (same region, phase-alternated)
  int tid = threadIdx.x;
  int wave = tid>>6, l = tid&63, lo16 = l&15, quad = l>>4;
  int m0 = blockIdx.x*128;
  // ---- LN2 on the block's 128x128 tile: thread = (px, 32-ch quarter), 2 iters ----
  #pragma unroll
  for (int itn=0; itn<2; itn++){
    int px = (tid>>2) + itn*64;
    int q = tid&3;
    const float* xr = X2 + (size_t)(m0+px)*128 + q*32;
    float v[32];
    #pragma unroll
    for (int i=0;i<8;i++) *(float4*)(v+i*4) = *(const float4*)(xr+i*4);
    float s=0.f, ss=0.f;
    #pragma unroll
    for (int i=0;i<32;i++){ s += v[i]; ss += v[i]*v[i]; }
    s  += __shfl_xor(s,1,64);  ss += __shfl_xor(ss,1,64);
    s  += __shfl_xor(s,2,64);  ss += __shfl_xor(ss,2,64);
    float mean = s*(1.f/CC), var = ss*(1.f/CC)-mean*mean, rstd = rsqrtf(var+1e-5f);
    const float* gp = lng + q*32; const float* bp = lnb + q*32;
    uint4* dst = (uint4*)(&h0s[px*136 + q*32]);
    #pragma unroll
    for (int i=0;i<4;i++){
      float4 g0 = *(const float4*)(gp+i*8),  g1 = *(const float4*)(gp+i*8+4);
      float4 c0v = *(const float4*)(bp+i*8), c1v = *(const float4*)(bp+i*8+4);
      float o0 = (v[i*8+0]-mean)*rstd*g0.x + c0v.x;
      float o1 = (v[i*8+1]-mean)*rstd*g0.y + c0v.y;
      float o2 = (v[i*8+2]-mean)*rstd*g0.z + c0v.z;
      float o3 = (v[i*8+3]-mean)*rstd*g0.w + c0v.w;
      float o4 = (v[i*8+4]-mean)*rstd*g1.x + c1v.x;
      float o5 = (v[i*8+5]-mean)*rstd*g1.y + c1v.y;
      float o6 = (v[i*8+6]-mean)*rstd*g1.z + c1v.z;
      float o7 = (v[i*8+7]-mean)*rstd*g1.w + c1v.w;
      uint4 up; up.x = pk(o0,o1); up.y = pk(o2,o3); up.z = pk(o4,o5); up.w = pk(o6,o7);
      dst[i] = up;
    }
  }
  __syncthreads();
  // a1 frags: wave owns 32 rows (2 m-tiles)
  short8 a1[2][4];
  #pragma unroll
  for (int mt=0;mt<2;mt++)
    #pragma unroll
    for (int ks=0;ks<4;ks++)
      a1[mt][ks] = *(const short8*)(&h0s[(wave*32 + mt*16 + lo16)*136 + ks*32 + quad*8]);
  f32x4 z = {0.f,0.f,0.f,0.f};
  f32x4 acc2[2][8];
  #pragma unroll
  for (int mt=0;mt<2;mt++)
    #pragma unroll
    for (int nt=0;nt<8;nt++) acc2[mt][nt]=z;

  for (int c0=0;c0<512;c0+=64){
    __syncthreads();   // prior GEMM2 wstage reads done; (c0=0: a1 loads done -> ts alias safe)
    #pragma unroll
    for (int it=0;it<4;it++){   // stage w1 chunk: rows c0..c0+63 of w1t
      int e = it*2048 + tid*8;
      int nn = e>>7, kk = e&127;
      *(uint4*)(&w1s[nn*136 + kk]) = *(const uint4*)(w1t + (size_t)(c0+nn)*128 + kk);
    }
    __syncthreads();
    // GEMM1: t(128x64) = h0 @ w1[:, c0:c0+64]; wave: 2 mt x 4 nt
    f32x4 acc1[2][4];
    #pragma unroll
    for (int mt=0;mt<2;mt++)
      #pragma unroll
      for (int nt=0;nt<4;nt++) acc1[mt][nt]=z;
    #pragma unroll
    for (int ks=0;ks<4;ks++)
      #pragma unroll
      for (int nt=0;nt<4;nt++){
        short8 bfr = *(const short8*)(&w1s[(nt*16+lo16)*136 + ks*32 + quad*8]);
        acc1[0][nt] = __builtin_amdgcn_mfma_f32_16x16x32_bf16(a1[0][ks], bfr, acc1[0][nt], 0,0,0);
        acc1[1][nt] = __builtin_amdgcn_mfma_f32_16x16x32_bf16(a1[1][ks], bfr, acc1[1][nt], 0,0,0);
      }
    #pragma unroll
    for (int mt=0;mt<2;mt++)
      #pragma unroll
      for (int nt=0;nt<4;nt++){
        float bb = b1[c0 + nt*16 + lo16];
        #pragma unroll
        for (int r=0;r<4;r++)
          ts[(wave*32 + mt*16 + quad*4 + r)*72 + nt*16 + lo16] = f2b(gelu_f(acc1[mt][nt][r] + bb));
      }
    __syncthreads();   // GEMM1 w1s reads + ts writes complete
    #pragma unroll
    for (int it=0;it<4;it++){   // stage w2 chunk: all 128 n-rows, k-cols c0..c0+63
      int e = it*2048 + tid*8;
      int nn = e>>6, kk = e&63;
      *(uint4*)(&w2s[nn*72 + kk]) = *(const uint4*)(w2t + (size_t)nn*512 + c0 + kk);
    }
    __syncthreads();
    // GEMM2: acc2 += t @ w2[c0:c0+64, :]; wave: 2 mt x 8 nt2, ks2 x2
    #pragma unroll
    for (int ks2=0;ks2<2;ks2++){
      short8 a2[2];
      #pragma unroll
      for (int mt=0;mt<2;mt++)
        a2[mt] = *(const short8*)(&ts[(wave*32 + mt*16 + lo16)*72 + ks2*32 + quad*8]);
      #pragma unroll
      for (int nt2=0;nt2<8;nt2++){
        short8 bfr2 = *(const short8*)(&w2s[(nt2*16+lo16)*72 + ks2*32 + quad*8]);
        acc2[0][nt2] = __builtin_amdgcn_mfma_f32_16x16x32_bf16(a2[0], bfr2, acc2[0][nt2], 0,0,0);
        acc2[1][nt2] = __builtin_amdgcn_mfma_f32_16x16x32_bf16(a2[1], bfr2, acc2[1][nt2], 0,0,0);
      }
    }
  }
  #pragma unroll
  for (int mt=0;mt<2;mt++)
    #pragma unroll
    for (int nt=0;nt<8;nt++){
      int col = nt*16 + lo16;
      float bb = b2[col];
      #pragma unroll
      for (int r=0;r<4;r++){
        int row = m0 + wave*32 + mt*16 + quad*4 + r;
        float v = acc2[mt][nt][r] + bb + X2[(size_t)row*128 + col];
        OUT[(size_t)row*128 + col] = v;
      }
    }
}

extern "C" void kernel_launch(void* const* d_in, const int* in_sizes, int n_in,
                              void* d_out, int out_size, void* d_ws, size_t ws_size,
                              hipStream_t stream)
{
  const float* x    = (const float*)d_in[0];
  const float* ln1g = (const float*)d_in[1];
  const float* ln1b = (const float*)d_in[2];
  const float* inw  = (const float*)d_in[3];
  const float* inb  = (const float*)d_in[4];
  const float* dwk  = (const float*)d_in[5];
  const float* dwb  = (const float*)d_in[6];
  const float* dwlng= (const float*)d_in[7];
  const float* dwlnb= (const float*)d_in[8];
  const float* offw = (const float*)d_in[9];
  const float* offb = (const float*)d_in[10];
  const float* maskw= (const float*)d_in[11];
  const float* maskb= (const float*)d_in[12];
  const float* outw = (const float*)d_in[13];
  const float* outb = (const float*)d_in[14];
  const float* ln2g = (const float*)d_in[15];
  const float* ln2b = (const float*)d_in[16];
  const float* fc1w = (const float*)d_in[17];
  const float* fc1b = (const float*)d_in[18];
  const float* fc2w = (const float*)d_in[19];
  const float* fc2b = (const float*)d_in[20];
  float* out = (float*)d_out;

  bf16* ws = (bf16*)d_ws;
  const size_t S = (size_t)NHW*CC;
  // ws: R0 [0,S): xn->y | R1 [S,2S): xp | R2 [2S,3S): x1 | [3S,..): weights
  bf16* xn = ws;
  bf16* xp = ws + S;
  bf16* x1 = ws + 2*S;
  bf16* y  = xn;
  float* x2 = out;
  bf16* inwt  = ws + 3*S;            // 128*128
  bf16* outwt = inwt + 128*128;      // 128*128
  bf16* w1t   = outwt + 128*128;     // 512*128
  bf16* w2t   = w1t + 512*128;       // 128*512
  bf16* wsw   = w2t + 128*512;       // 224*128
  float* cw   = (float*)(wsw + 224*128);  // 224 f32

  // 0. pre-pack weights (bf16, [n][k])
  tr_k<<<64, 256, 0, stream>>>(inw,  inwt, 7, 128, 128*128);
  tr_k<<<64, 256, 0, stream>>>(outw, outwt,7, 128, 128*128);
  tr_k<<<256,256, 0, stream>>>(fc1w, w1t,  7, 512, 512*128);
  tr_k<<<256,256, 0, stream>>>(fc2w, w2t,  9, 128, 128*512);
  packw_k<<<112,256, 0, stream>>>(offw, offb, maskw, maskb, wsw, cw);
  // 1. xn = LN1(x)
  ln_k<<<NHW/4, 256, 0, stream>>>(x, ln1g, ln1b, xn);
  // 2. xp = xn @ in_w + in_b   [MFMA]
  gemm_mfma<bf16,false><<<dim3(2,256), 256, 0, stream>>>(xn, inwt, inb, nullptr, xp);
  // 3. x1 = gelu(LN(dwconv(xn)))
  convln_k<<<NHW/16, 256, 0, stream>>>(xn, dwk, dwb, dwlng, dwlnb, x1);
  // 4. y = dcn_core(xp, offset(x1), mask(x1))
  samp_k<<<NHW/32, 256, 0, stream>>>(x1, xp, wsw, cw, y);
  // 5. x2 = x + (y @ out_w + out_b)   [MFMA, f32 into d_out]
  gemm_mfma<float,true><<<dim3(2,256), 256, 0, stream>>>(y, outwt, outb, x, x2);
  // 6+7. out = x2 + gelu(LN2(x2) @ fc1 + b1) @ fc2 + b2   [fused, in-place d_out]
  mlp_mfma<<<NHW/128, 256, 0, stream>>>(x2, ln2g, ln2b, w1t, fc1b, w2t, fc2b, out);
}

// Round 9
// 282.829 us; speedup vs baseline: 3.4279x; 1.0757x over previous
//
#include <hip/hip_runtime.h>
#include <hip/hip_bf16.h>
#include <math.h>

#define NB 4
#define HH 128
#define WW 128
#define CC 128
#define GG 8
#define GCC 16
#define KK 9
#define NHW (NB*HH*WW)   // 65536

typedef __hip_bfloat16 bf16;
typedef __attribute__((ext_vector_type(8))) short short8;
typedef __attribute__((ext_vector_type(4))) float f32x4;

__device__ __forceinline__ float b2f(bf16 v){ return __bfloat162float(v); }
__device__ __forceinline__ bf16 f2b(float v){ return __float2bfloat16(v); }
__device__ __forceinline__ float gelu_f(float v){ return 0.5f*v*(1.f+erff(v*0.70710678118654752f)); }
__device__ __forceinline__ float lo_bf(unsigned u){ union{unsigned i; float f;} c; c.i = u<<16; return c.f; }
__device__ __forceinline__ float hi_bf(unsigned u){ union{unsigned i; float f;} c; c.i = u&0xffff0000u; return c.f; }
__device__ __forceinline__ unsigned pk(float a, float b){
  return ((unsigned)__bfloat16_as_ushort(f2b(b))<<16) | (unsigned)__bfloat16_as_ushort(f2b(a));
}
__device__ __forceinline__ void st_out(bf16* p, float v){ *p = f2b(v); }
__device__ __forceinline__ void st_out(float* p, float v){ *p = v; }
__device__ __forceinline__ void acc8(float* a, uint4 u, float w){
  a[0]+=w*lo_bf(u.x); a[1]+=w*hi_bf(u.x); a[2]+=w*lo_bf(u.y); a[3]+=w*hi_bf(u.y);
  a[4]+=w*lo_bf(u.z); a[5]+=w*hi_bf(u.z); a[6]+=w*lo_bf(u.w); a[7]+=w*hi_bf(u.w);
}

// ---- fused weight prep: 4 transposes + DCN pack, one launch ----
// ranges: [0,16k) inwt | [16k,32k) outwt | [32k,96k) w1t | [96k,160k) w2t
//         | [160k,188k) wsw | [188k, 188k+224) cw
__global__ __launch_bounds__(256) void prep_k(
    const float* __restrict__ inw,  const float* __restrict__ outw,
    const float* __restrict__ fc1w, const float* __restrict__ fc2w,
    const float* __restrict__ offw, const float* __restrict__ offb,
    const float* __restrict__ maskw,const float* __restrict__ maskb,
    bf16* __restrict__ inwt, bf16* __restrict__ outwt,
    bf16* __restrict__ w1t,  bf16* __restrict__ w2t,
    bf16* __restrict__ wsw,  float* __restrict__ cw)
{
  int idx = blockIdx.x*256 + threadIdx.x;
  if (idx < 16384){
    int n = idx>>7, k = idx&127;
    inwt[idx] = f2b(inw[(size_t)k*128 + n]);
  } else if (idx < 32768){
    int i = idx-16384; int n = i>>7, k = i&127;
    outwt[i] = f2b(outw[(size_t)k*128 + n]);
  } else if (idx < 98304){
    int i = idx-32768; int n = i>>7, k = i&127;
    w1t[i] = f2b(fc1w[(size_t)k*512 + n]);
  } else if (idx < 163840){
    int i = idx-98304; int n = i>>9, k = i&511;
    w2t[i] = f2b(fc2w[(size_t)k*128 + n]);
  } else if (idx < 192512){
    int i = idx-163840; int nn = i>>7, k = i&127;
    float v = (nn<144) ? offw[(size_t)k*144+nn] : (nn<216 ? maskw[(size_t)k*72+(nn-144)] : 0.f);
    wsw[i] = f2b(v);
  } else if (idx < 192736){
    int i = idx-192512;
    cw[i] = (i<144) ? offb[i] : (i<216 ? maskb[i-144] : 0.f);
  }
}

// ---------------- LayerNorm over C=128, one wave per pixel ----------------
__global__ __launch_bounds__(256) void ln_k(const float* __restrict__ X,
    const float* __restrict__ gam, const float* __restrict__ bet, bf16* __restrict__ Y)
{
  int lane = threadIdx.x & 63;
  int wid  = threadIdx.x >> 6;
  size_t pix = (size_t)blockIdx.x*4 + wid;
  const float* xp = X + pix*CC;
  int c0 = lane*2;
  float v0 = xp[c0], v1 = xp[c0+1];
  float s = v0+v1, ss = v0*v0+v1*v1;
  #pragma unroll
  for (int off=32; off>0; off>>=1){ s += __shfl_xor(s,off,64); ss += __shfl_xor(ss,off,64); }
  float mean = s*(1.f/CC);
  float var  = ss*(1.f/CC) - mean*mean;
  float rstd = rsqrtf(var + 1e-5f);
  float y0 = (v0-mean)*rstd*gam[c0]   + bet[c0];
  float y1 = (v1-mean)*rstd*gam[c0+1] + bet[c0+1];
  Y[pix*CC + c0]   = f2b(y0);
  Y[pix*CC + c0+1] = f2b(y1);
}

// -------- depthwise 3x3 conv + LN + GELU: 16 px x 16 ch-groups, no LDS --------
__global__ __launch_bounds__(256) void convln_k(const bf16* __restrict__ XN,
    const float* __restrict__ dwk, const float* __restrict__ dwb,
    const float* __restrict__ gam, const float* __restrict__ bet, bf16* __restrict__ X1)
{
  int tid = threadIdx.x;
  int px = tid>>4, cg = tid&15;
  int ch0 = cg*8;
  int pix = blockIdx.x*16 + px;           // 16 px stay within one row (128%16==0)
  int w = pix & (WW-1), h = (pix>>7)&(HH-1), n = pix>>14;
  float acc[8];
  {
    float4 b0 = *(const float4*)(dwb + ch0), b1 = *(const float4*)(dwb + ch0 + 4);
    acc[0]=b0.x; acc[1]=b0.y; acc[2]=b0.z; acc[3]=b0.w;
    acc[4]=b1.x; acc[5]=b1.y; acc[6]=b1.z; acc[7]=b1.w;
  }
  #pragma unroll
  for (int ky=0;ky<3;ky++){
    int yy = h+ky-1; if ((unsigned)yy>=(unsigned)HH) continue;
    #pragma unroll
    for (int kx=0;kx<3;kx++){
      int xx = w+kx-1; if ((unsigned)xx>=(unsigned)WW) continue;
      uint4 u = *(const uint4*)(XN + ((size_t)((n*HH+yy)*WW+xx))*CC + ch0);
      const float* wp = dwk + (ky*3+kx)*CC + ch0;
      float4 w0 = *(const float4*)wp; float4 w1 = *(const float4*)(wp+4);
      acc[0] += lo_bf(u.x)*w0.x; acc[1] += hi_bf(u.x)*w0.y;
      acc[2] += lo_bf(u.y)*w0.z; acc[3] += hi_bf(u.y)*w0.w;
      acc[4] += lo_bf(u.z)*w1.x; acc[5] += hi_bf(u.z)*w1.y;
      acc[6] += lo_bf(u.w)*w1.z; acc[7] += hi_bf(u.w)*w1.w;
    }
  }
  float s=0.f, ss=0.f;
  #pragma unroll
  for (int i=0;i<8;i++){ s += acc[i]; ss += acc[i]*acc[i]; }
  #pragma unroll
  for (int off=1; off<16; off<<=1){ s += __shfl_xor(s,off,64); ss += __shfl_xor(ss,off,64); }
  float mean=s*(1.f/CC), var=ss*(1.f/CC)-mean*mean, rstd=rsqrtf(var+1e-5f);
  float4 g0 = *(const float4*)(gam + ch0), g1 = *(const float4*)(gam + ch0 + 4);
  float4 be0 = *(const float4*)(bet + ch0), be1 = *(const float4*)(bet + ch0 + 4);
  float gv[8] = {g0.x,g0.y,g0.z,g0.w,g1.x,g1.y,g1.z,g1.w};
  float bv[8] = {be0.x,be0.y,be0.z,be0.w,be1.x,be1.y,be1.z,be1.w};
  float o[8];
  #pragma unroll
  for (int i=0;i<8;i++) o[i] = gelu_f((acc[i]-mean)*rstd*gv[i] + bv[i]);
  uint4 up; up.x = pk(o[0],o[1]); up.y = pk(o[2],o[3]); up.z = pk(o[4],o[5]); up.w = pk(o[6],o[7]);
  *(uint4*)(X1 + (size_t)pix*CC + ch0) = up;
}

// ---- fused DCN: MFMA projection + softmax + branchless bilinear sampling ----
#define OMS 226   // oms row stride (bf16): 113 dwords, odd -> banks spread
__global__ __launch_bounds__(256) void samp_k(const bf16* __restrict__ X1,
    const bf16* __restrict__ XP,
    const bf16* __restrict__ wsw, const float* __restrict__ cw,
    bf16* __restrict__ Y)
{
  __shared__ bf16 oms[32*OMS];   // 14464 B
  int tid = threadIdx.x;
  int pix0 = blockIdx.x*32;      // 32 px within one row segment
  int wave = tid>>6, l = tid&63, lo16 = l&15, quad = l>>4;
  // ---- phase 1: scores(32x224) = x1[pix0:pix0+32] @ wsw^T + cw, MFMA ----
  int nt0 = wave*4;
  int ntn = (wave==3) ? 2 : 4;
  short8 af[2][4];
  #pragma unroll
  for (int mt=0;mt<2;mt++)
    #pragma unroll
    for (int ks=0;ks<4;ks++)
      af[mt][ks] = *(const short8*)(X1 + (size_t)(pix0+mt*16+lo16)*128 + ks*32 + quad*8);
  f32x4 z = {0.f,0.f,0.f,0.f};
  f32x4 acc[2][4];
  #pragma unroll
  for (int mt=0;mt<2;mt++)
    #pragma unroll
    for (int t=0;t<4;t++) acc[mt][t]=z;
  for (int t=0;t<ntn;t++){
    int nt = nt0+t;
    #pragma unroll
    for (int ks=0;ks<4;ks++){
      short8 bfr = *(const short8*)(wsw + (size_t)(nt*16+lo16)*128 + ks*32 + quad*8);
      acc[0][t] = __builtin_amdgcn_mfma_f32_16x16x32_bf16(af[0][ks], bfr, acc[0][t], 0,0,0);
      acc[1][t] = __builtin_amdgcn_mfma_f32_16x16x32_bf16(af[1][ks], bfr, acc[1][t], 0,0,0);
    }
  }
  for (int t=0;t<ntn;t++){
    int col = (nt0+t)*16 + lo16;
    float bb = cw[col];
    #pragma unroll
    for (int mt=0;mt<2;mt++)
      #pragma unroll
      for (int r=0;r<4;r++)
        oms[(mt*16 + quad*4 + r)*OMS + col] = f2b(acc[mt][t][r] + bb);
  }
  __syncthreads();
  // ---- phase 2: softmax, task = (px, group), 32*8 = 256 ----
  {
    int m = tid>>3, g = tid&7;
    int base = m*OMS + 144 + g*9;
    float sc[9]; float mx = -1e30f;
    #pragma unroll
    for (int k=0;k<9;k++){ sc[k] = b2f(oms[base+k]); mx = fmaxf(mx, sc[k]); }
    float sum = 0.f;
    #pragma unroll
    for (int k=0;k<9;k++){ sc[k] = expf(sc[k]-mx); sum += sc[k]; }
    float inv = 1.f/sum;
    #pragma unroll
    for (int k=0;k<9;k++) oms[base+k] = f2b(sc[k]*inv);
  }
  __syncthreads();
  // ---- phase 3: branchless sampling; lane = ch-oct, slot = tid>>4 ----
  // clamp coords to [0,127] (always-legal address), fold validity into weight
  int oct = tid&15, sl = tid>>4;
  int g = oct>>1;
  int ch = g*GCC + (oct&1)*8;
  int w0 = pix0 & (WW-1);
  int h  = (pix0>>7) & (HH-1);
  int n  = pix0>>14;
  const bf16* base = XP + (size_t)n*HH*WW*CC + ch;
  for (int it=0; it<2; it++){
    int m = it*16 + sl;
    int wc = w0 + m;
    const bf16* omrow = &oms[m*OMS];
    float a[8] = {0.f,0.f,0.f,0.f,0.f,0.f,0.f,0.f};
    #pragma unroll
    for (int k=0;k<9;k++){
      float offx = b2f(omrow[g*18 + 2*k]);
      float offy = b2f(omrow[g*18 + 2*k + 1]);
      float mk   = b2f(omrow[144 + g*9 + k]);
      float pxf = (float)(wc + (k/3) - 1) + offx;   // x-major grid
      float pyf = (float)(h  + (k%3) - 1) + offy;
      float x0f = floorf(pxf), y0f = floorf(pyf);
      float txf = pxf-x0f,     tyf = pyf-y0f;
      int x0 = (int)x0f, y0 = (int)y0f;
      int x1i = x0+1,    y1i = y0+1;
      float vx0 = ((unsigned)x0 <(unsigned)WW)?1.f:0.f;
      float vx1 = ((unsigned)x1i<(unsigned)WW)?1.f:0.f;
      float vy0 = ((unsigned)y0 <(unsigned)HH)?1.f:0.f;
      float vy1 = ((unsigned)y1i<(unsigned)HH)?1.f:0.f;
      int cx0 = min(max(x0,0),WW-1),  cx1 = min(max(x1i,0),WW-1);
      int cy0 = min(max(y0,0),HH-1),  cy1 = min(max(y1i,0),HH-1);
      float w00=(1.f-tyf)*(1.f-txf)*mk*vy0*vx0, w01=(1.f-tyf)*txf*mk*vy0*vx1;
      float w10=tyf*(1.f-txf)*mk*vy1*vx0,       w11=tyf*txf*mk*vy1*vx1;
      uint4 u00 = *(const uint4*)(base + ((size_t)(cy0*WW+cx0))*CC);
      uint4 u01 = *(const uint4*)(base + ((size_t)(cy0*WW+cx1))*CC);
      uint4 u10 = *(const uint4*)(base + ((size_t)(cy1*WW+cx0))*CC);
      uint4 u11 = *(const uint4*)(base + ((size_t)(cy1*WW+cx1))*CC);
      acc8(a,u00,w00); acc8(a,u01,w01); acc8(a,u10,w10); acc8(a,u11,w11);
    }
    uint4 outp;
    outp.x = pk(a[0],a[1]); outp.y = pk(a[2],a[3]);
    outp.z = pk(a[4],a[5]); outp.w = pk(a[6],a[7]);
    *(uint4*)(Y + (size_t)(pix0+m)*CC + ch) = outp;
  }
}

// ------------- MFMA GEMM: C(Mx128) = A(Mx128 bf16) @ Bt^T + bias (+res) -------------
// 4 m-tiles per wave (B-frag reuse 4). Block = 256 rows, grid (2, 256).
template<typename OutT, bool RES>
__global__ __launch_bounds__(256) void gemm_mfma(const bf16* __restrict__ A,
    const bf16* __restrict__ Bt, const float* __restrict__ bias,
    const float* __restrict__ res, OutT* __restrict__ C)
{
  int tid = threadIdx.x;
  int wave = tid>>6, l = tid&63, lo16 = l&15, quad = l>>4;
  int m0 = blockIdx.y*256 + wave*64;
  int n0 = blockIdx.x*64;
  short8 bfr[4][4];   // [kstep][ntile]
  #pragma unroll
  for (int ks=0;ks<4;ks++)
    #pragma unroll
    for (int nt=0;nt<4;nt++)
      bfr[ks][nt] = *(const short8*)(Bt + (size_t)(n0+nt*16+lo16)*128 + ks*32 + quad*8);
  f32x4 z = {0.f,0.f,0.f,0.f};
  f32x4 acc[4][4];
  #pragma unroll
  for (int mt=0;mt<4;mt++)
    #pragma unroll
    for (int nt=0;nt<4;nt++) acc[mt][nt]=z;
  #pragma unroll
  for (int ks=0;ks<4;ks++){
    short8 af[4];
    #pragma unroll
    for (int mt=0;mt<4;mt++)
      af[mt] = *(const short8*)(A + (size_t)(m0+mt*16+lo16)*128 + ks*32 + quad*8);
    #pragma unroll
    for (int nt=0;nt<4;nt++)
      #pragma unroll
      for (int mt=0;mt<4;mt++)
        acc[mt][nt] = __builtin_amdgcn_mfma_f32_16x16x32_bf16(af[mt], bfr[ks][nt], acc[mt][nt], 0,0,0);
  }
  #pragma unroll
  for (int mt=0;mt<4;mt++)
    #pragma unroll
    for (int nt=0;nt<4;nt++){
      int col = n0 + nt*16 + lo16;
      float bb = bias[col];
      #pragma unroll
      for (int r=0;r<4;r++){
        int row = m0 + mt*16 + quad*4 + r;
        float v = acc[mt][nt][r] + bb;
        if (RES) v += res[(size_t)row*128 + col];
        st_out(&C[(size_t)row*128 + col], v);
      }
    }
}

// ---- fused MFMA MLP with internal LN2, LDS-staged weights, 128 px/block ----
__global__ __launch_bounds__(256) void mlp_mfma(const float* __restrict__ X2,
    const float* __restrict__ lng, const float* __restrict__ lnb,
    const bf16* __restrict__ w1t, const float* __restrict__ b1,
    const bf16* __restrict__ w2t, const float* __restrict__ b2,
    float* __restrict__ OUT)
{
  __shared__ __align__(16) char smem[34816 + 18432];
  bf16* h0s = (bf16*)smem;             // 128 x 136
  bf16* ts  = (bf16*)smem;             // 128 x 72 (aliases h0s after a1 loads)
  bf16* w1s = (bf16*)(smem + 34816);   // 64 x 136
  bf16* w2s = (bf16*)(smem + 34816);   // 128 x 72 (same region, phase-alternated)
  int tid = threadIdx.x;
  int wave = tid>>6, l = tid&63, lo16 = l&15, quad = l>>4;
  int m0 = blockIdx.x*128;
  #pragma unroll
  for (int itn=0; itn<2; itn++){
    int px = (tid>>2) + itn*64;
    int q = tid&3;
    const float* xr = X2 + (size_t)(m0+px)*128 + q*32;
    float v[32];
    #pragma unroll
    for (int i=0;i<8;i++) *(float4*)(v+i*4) = *(const float4*)(xr+i*4);
    float s=0.f, ss=0.f;
    #pragma unroll
    for (int i=0;i<32;i++){ s += v[i]; ss += v[i]*v[i]; }
    s  += __shfl_xor(s,1,64);  ss += __shfl_xor(ss,1,64);
    s  += __shfl_xor(s,2,64);  ss += __shfl_xor(ss,2,64);
    float mean = s*(1.f/CC), var = ss*(1.f/CC)-mean*mean, rstd = rsqrtf(var+1e-5f);
    const float* gp = lng + q*32; const float* bp = lnb + q*32;
    uint4* dst = (uint4*)(&h0s[px*136 + q*32]);
    #pragma unroll
    for (int i=0;i<4;i++){
      float4 g0 = *(const float4*)(gp+i*8),  g1 = *(const float4*)(gp+i*8+4);
      float4 c0v = *(const float4*)(bp+i*8), c1v = *(const float4*)(bp+i*8+4);
      float o0 = (v[i*8+0]-mean)*rstd*g0.x + c0v.x;
      float o1 = (v[i*8+1]-mean)*rstd*g0.y + c0v.y;
      float o2 = (v[i*8+2]-mean)*rstd*g0.z + c0v.z;
      float o3 = (v[i*8+3]-mean)*rstd*g0.w + c0v.w;
      float o4 = (v[i*8+4]-mean)*rstd*g1.x + c1v.x;
      float o5 = (v[i*8+5]-mean)*rstd*g1.y + c1v.y;
      float o6 = (v[i*8+6]-mean)*rstd*g1.z + c1v.z;
      float o7 = (v[i*8+7]-mean)*rstd*g1.w + c1v.w;
      uint4 up; up.x = pk(o0,o1); up.y = pk(o2,o3); up.z = pk(o4,o5); up.w = pk(o6,o7);
      dst[i] = up;
    }
  }
  __syncthreads();
  short8 a1[2][4];
  #pragma unroll
  for (int mt=0;mt<2;mt++)
    #pragma unroll
    for (int ks=0;ks<4;ks++)
      a1[mt][ks] = *(const short8*)(&h0s[(wave*32 + mt*16 + lo16)*136 + ks*32 + quad*8]);
  f32x4 z = {0.f,0.f,0.f,0.f};
  f32x4 acc2[2][8];
  #pragma unroll
  for (int mt=0;mt<2;mt++)
    #pragma unroll
    for (int nt=0;nt<8;nt++) acc2[mt][nt]=z;

  for (int c0=0;c0<512;c0+=64){
    __syncthreads();
    #pragma unroll
    for (int it=0;it<4;it++){
      int e = it*2048 + tid*8;
      int nn = e>>7, kk = e&127;
      *(uint4*)(&w1s[nn*136 + kk]) = *(const uint4*)(w1t + (size_t)(c0+nn)*128 + kk);
    }
    __syncthreads();
    f32x4 acc1[2][4];
    #pragma unroll
    for (int mt=0;mt<2;mt++)
      #pragma unroll
      for (int nt=0;nt<4;nt++) acc1[mt][nt]=z;
    #pragma unroll
    for (int ks=0;ks<4;ks++)
      #pragma unroll
      for (int nt=0;nt<4;nt++){
        short8 bfr = *(const short8*)(&w1s[(nt*16+lo16)*136 + ks*32 + quad*8]);
        acc1[0][nt] = __builtin_amdgcn_mfma_f32_16x16x32_bf16(a1[0][ks], bfr, acc1[0][nt], 0,0,0);
        acc1[1][nt] = __builtin_amdgcn_mfma_f32_16x16x32_bf16(a1[1][ks], bfr, acc1[1][nt], 0,0,0);
      }
    #pragma unroll
    for (int mt=0;mt<2;mt++)
      #pragma unroll
      for (int nt=0;nt<4;nt++){
        float bb = b1[c0 + nt*16 + lo16];
        #pragma unroll
        for (int r=0;r<4;r++)
          ts[(wave*32 + mt*16 + quad*4 + r)*72 + nt*16 + lo16] = f2b(gelu_f(acc1[mt][nt][r] + bb));
      }
    __syncthreads();
    #pragma unroll
    for (int it=0;it<4;it++){
      int e = it*2048 + tid*8;
      int nn = e>>6, kk = e&63;
      *(uint4*)(&w2s[nn*72 + kk]) = *(const uint4*)(w2t + (size_t)nn*512 + c0 + kk);
    }
    __syncthreads();
    #pragma unroll
    for (int ks2=0;ks2<2;ks2++){
      short8 a2[2];
      #pragma unroll
      for (int mt=0;mt<2;mt++)
        a2[mt] = *(const short8*)(&ts[(wave*32 + mt*16 + lo16)*72 + ks2*32 + quad*8]);
      #pragma unroll
      for (int nt2=0;nt2<8;nt2++){
        short8 bfr2 = *(const short8*)(&w2s[(nt2*16+lo16)*72 + ks2*32 + quad*8]);
        acc2[0][nt2] = __builtin_amdgcn_mfma_f32_16x16x32_bf16(a2[0], bfr2, acc2[0][nt2], 0,0,0);
        acc2[1][nt2] = __builtin_amdgcn_mfma_f32_16x16x32_bf16(a2[1], bfr2, acc2[1][nt2], 0,0,0);
      }
    }
  }
  #pragma unroll
  for (int mt=0;mt<2;mt++)
    #pragma unroll
    for (int nt=0;nt<8;nt++){
      int col = nt*16 + lo16;
      float bb = b2[col];
      #pragma unroll
      for (int r=0;r<4;r++){
        int row = m0 + wave*32 + mt*16 + quad*4 + r;
        float v = acc2[mt][nt][r] + bb + X2[(size_t)row*128 + col];
        OUT[(size_t)row*128 + col] = v;
      }
    }
}

extern "C" void kernel_launch(void* const* d_in, const int* in_sizes, int n_in,
                              void* d_out, int out_size, void* d_ws, size_t ws_size,
                              hipStream_t stream)
{
  const float* x    = (const float*)d_in[0];
  const float* ln1g = (const float*)d_in[1];
  const float* ln1b = (const float*)d_in[2];
  const float* inw  = (const float*)d_in[3];
  const float* inb  = (const float*)d_in[4];
  const float* dwk  = (const float*)d_in[5];
  const float* dwb  = (const float*)d_in[6];
  const float* dwlng= (const float*)d_in[7];
  const float* dwlnb= (const float*)d_in[8];
  const float* offw = (const float*)d_in[9];
  const float* offb = (const float*)d_in[10];
  const float* maskw= (const float*)d_in[11];
  const float* maskb= (const float*)d_in[12];
  const float* outw = (const float*)d_in[13];
  const float* outb = (const float*)d_in[14];
  const float* ln2g = (const float*)d_in[15];
  const float* ln2b = (const float*)d_in[16];
  const float* fc1w = (const float*)d_in[17];
  const float* fc1b = (const float*)d_in[18];
  const float* fc2w = (const float*)d_in[19];
  const float* fc2b = (const float*)d_in[20];
  float* out = (float*)d_out;

  bf16* ws = (bf16*)d_ws;
  const size_t S = (size_t)NHW*CC;
  // ws: R0 [0,S): xn->y | R1 [S,2S): xp | R2 [2S,3S): x1 | [3S,..): weights
  bf16* xn = ws;
  bf16* xp = ws + S;
  bf16* x1 = ws + 2*S;
  bf16* y  = xn;
  float* x2 = out;
  bf16* inwt  = ws + 3*S;            // 128*128
  bf16* outwt = inwt + 128*128;      // 128*128
  bf16* w1t   = outwt + 128*128;     // 512*128
  bf16* w2t   = w1t + 512*128;       // 128*512
  bf16* wsw   = w2t + 128*512;       // 224*128
  float* cw   = (float*)(wsw + 224*128);  // 224 f32

  // 0. fused weight prep (one launch)
  prep_k<<<753, 256, 0, stream>>>(inw, outw, fc1w, fc2w, offw, offb, maskw, maskb,
                                  inwt, outwt, w1t, w2t, wsw, cw);
  // 1. xn = LN1(x)
  ln_k<<<NHW/4, 256, 0, stream>>>(x, ln1g, ln1b, xn);
  // 2. xp = xn @ in_w + in_b   [MFMA]
  gemm_mfma<bf16,false><<<dim3(2,256), 256, 0, stream>>>(xn, inwt, inb, nullptr, xp);
  // 3. x1 = gelu(LN(dwconv(xn)))
  convln_k<<<NHW/16, 256, 0, stream>>>(xn, dwk, dwb, dwlng, dwlnb, x1);
  // 4. y = dcn_core(xp, offset(x1), mask(x1))   [branchless sampling]
  samp_k<<<NHW/32, 256, 0, stream>>>(x1, xp, wsw, cw, y);
  // 5. x2 = x + (y @ out_w + out_b)   [MFMA, f32 into d_out]
  gemm_mfma<float,true><<<dim3(2,256), 256, 0, stream>>>(y, outwt, outb, x, x2);
  // 6+7. out = x2 + gelu(LN2(x2) @ fc1 + b1) @ fc2 + b2   [fused, in-place d_out]
  mlp_mfma<<<NHW/128, 256, 0, stream>>>(x2, ln2g, ln2b, w1t, fc1b, w2t, fc2b, out);
}